// Round 7
// baseline (443.099 us; speedup 1.0000x reference)
//
#include <hip/hip_runtime.h>

// GCN: 4 layers, N=50000, E=640000, d=128 (last 128->40).
// R7: agg = row-major gather, feature dim split into 4 chunks of 32 floats
// (one 128B line per edge-request). chunk = blockIdx&3 -> XCDs {c,c+4} via
// round-robin dispatch, so each XCD's L2 works a 6.4MB line-slice instead of
// the whole 25.6MB table. R5's locality + R6's request shape/concurrency.

#define DIM 128
#define CHUNK 1024        // scan chunk

__global__ void deg_kernel(const int* __restrict__ dst, int* __restrict__ deg, int E) {
    int i = blockIdx.x * blockDim.x + threadIdx.x;
    if (i < E) atomicAdd(&deg[dst[i]], 1);
}

// Phase A: per-chunk sums of deg; also computes nrm = rsqrt(max(deg,1)).
__global__ __launch_bounds__(256) void scanA_kernel(
        const int* __restrict__ deg, float* __restrict__ nrm,
        int* __restrict__ bsum, int n) {
    int b = blockIdx.x, t = threadIdx.x;
    int base = b * CHUNK + t * 4;
    int s = 0;
    if (base + 3 < n) {
        int4 d = *(const int4*)&deg[base];
        s = d.x + d.y + d.z + d.w;
        float4 r;
        r.x = rsqrtf(fmaxf((float)d.x, 1.0f));
        r.y = rsqrtf(fmaxf((float)d.y, 1.0f));
        r.z = rsqrtf(fmaxf((float)d.z, 1.0f));
        r.w = rsqrtf(fmaxf((float)d.w, 1.0f));
        *(float4*)&nrm[base] = r;
    } else {
        for (int j = 0; j < 4; ++j) {
            int idx = base + j;
            if (idx < n) {
                int d = deg[idx];
                s += d;
                nrm[idx] = rsqrtf(fmaxf((float)d, 1.0f));
            }
        }
    }
    for (int o = 32; o; o >>= 1) s += __shfl_down(s, o, 64);
    __shared__ int ws[4];
    if ((t & 63) == 0) ws[t >> 6] = s;
    __syncthreads();
    if (t == 0) bsum[b] = ws[0] + ws[1] + ws[2] + ws[3];
}

// Phase B: exclusive scan of bsum[G] in one wave (G <= 64); writes off[n]=total.
__global__ void scanB_kernel(int* __restrict__ bsum, int* __restrict__ off,
                             int G, int n) {
    int t = threadIdx.x;
    int orig = (t < G) ? bsum[t] : 0;
    int v = orig;
    for (int o = 1; o < 64; o <<= 1) {
        int u = __shfl_up(v, o, 64);
        if (t >= o) v += u;
    }
    if (t < G) bsum[t] = v - orig;
    if (t == G - 1) off[n] = v;
}

// Phase C: off[i] = bsum[chunk] + prefix within chunk. int4 coalesced.
__global__ __launch_bounds__(256) void scanC_kernel(
        const int* __restrict__ deg, const int* __restrict__ bsum,
        int* __restrict__ off, int n) {
    int b = blockIdx.x, t = threadIdx.x;
    int base = b * CHUNK + t * 4;
    int d0 = 0, d1 = 0, d2 = 0, d3 = 0;
    if (base + 3 < n) {
        int4 d = *(const int4*)&deg[base];
        d0 = d.x; d1 = d.y; d2 = d.z; d3 = d.w;
    } else {
        if (base     < n) d0 = deg[base];
        if (base + 1 < n) d1 = deg[base + 1];
        if (base + 2 < n) d2 = deg[base + 2];
    }
    int tot = d0 + d1 + d2 + d3;
    int v = tot;
    for (int o = 1; o < 64; o <<= 1) {
        int u = __shfl_up(v, o, 64);
        if ((t & 63) >= o) v += u;
    }
    __shared__ int wsum[4];
    if ((t & 63) == 63) wsum[t >> 6] = v;
    __syncthreads();
    int wbase = 0;
    for (int w = 0; w < (t >> 6); ++w) wbase += wsum[w];
    int p = bsum[b] + wbase + (v - tot);
    if (base + 3 < n) {
        int4 o4 = make_int4(p, p + d0, p + d0 + d1, p + d0 + d1 + d2);
        *(int4*)&off[base] = o4;
    } else {
        if (base     < n) off[base]     = p;
        if (base + 1 < n) off[base + 1] = p + d0;
        if (base + 2 < n) off[base + 2] = p + d0 + d1;
    }
}

__global__ void fill_kernel(const int* __restrict__ src, const int* __restrict__ dst,
                            const int* __restrict__ off, int* __restrict__ cur,
                            int* __restrict__ csr, int E) {
    int i = blockIdx.x * blockDim.x + threadIdx.x;
    if (i < E) {
        int d = dst[i];
        int p = atomicAdd(&cur[d], 1);
        csr[off[d] + p] = src[i];
    }
}

// bufA = features * nrm[row]  (row-major)
__global__ void scale_kernel(const float* __restrict__ f, const float* __restrict__ nrm,
                             float* __restrict__ out, int n4) {
    int i = blockIdx.x * blockDim.x + threadIdx.x;
    if (i < n4) {
        int r = i >> 5;
        float s = nrm[r];
        float4 v = ((const float4*)f)[i];
        v.x *= s; v.y *= s; v.z *= s; v.w *= s;
        ((float4*)out)[i] = v;
    }
}

// Chunked agg: chunk = bid&3 (32 floats = one 128B line of each row), wave
// handles one node. 8 edge-slots (sg = lane>>3) x 8 lanes (pos = lane&7,
// float4) -> 8 edges per wave-inst, full-line requests, 4-deep unroll.
// Reduce over slot bits via shfl_xor(8,16,32); slot-0 lanes write 128B.
__global__ __launch_bounds__(256) void agg_kernel(
        const float* __restrict__ hin, const float* __restrict__ nrm,
        const int* __restrict__ off, const int* __restrict__ csr,
        float* __restrict__ out, int N) {
    int bid = blockIdx.x;
    int chunk = bid & 3;
    int node = (bid >> 2) * 4 + (threadIdx.x >> 6);
    if (node >= N) return;
    int lane = threadIdx.x & 63;
    int pos = lane & 7, sg = lane >> 3;
    int c = chunk * 32 + pos * 4;
    int b = off[node], e = off[node + 1];
    float4 a0 = make_float4(0,0,0,0), a1 = a0, a2 = a0, a3 = a0;
    int j = b + sg;
    for (; j + 24 < e; j += 32) {           // 4-deep (fires for deg >= ~32)
        int s0 = csr[j], s1 = csr[j+8], s2 = csr[j+16], s3 = csr[j+24];
        float4 v0 = *(const float4*)&hin[(size_t)s0 * DIM + c];
        float4 v1 = *(const float4*)&hin[(size_t)s1 * DIM + c];
        float4 v2 = *(const float4*)&hin[(size_t)s2 * DIM + c];
        float4 v3 = *(const float4*)&hin[(size_t)s3 * DIM + c];
        a0.x+=v0.x; a0.y+=v0.y; a0.z+=v0.z; a0.w+=v0.w;
        a1.x+=v1.x; a1.y+=v1.y; a1.z+=v1.z; a1.w+=v1.w;
        a2.x+=v2.x; a2.y+=v2.y; a2.z+=v2.z; a2.w+=v2.w;
        a3.x+=v3.x; a3.y+=v3.y; a3.z+=v3.z; a3.w+=v3.w;
    }
    for (; j < e; j += 8) {                 // typical path (deg ~ 12.8)
        float4 v = *(const float4*)&hin[(size_t)csr[j] * DIM + c];
        a0.x+=v.x; a0.y+=v.y; a0.z+=v.z; a0.w+=v.w;
    }
    float4 r;
    r.x = (a0.x+a1.x) + (a2.x+a3.x);
    r.y = (a0.y+a1.y) + (a2.y+a3.y);
    r.z = (a0.z+a1.z) + (a2.z+a3.z);
    r.w = (a0.w+a1.w) + (a2.w+a3.w);
    r.x += __shfl_xor(r.x,  8, 64);
    r.y += __shfl_xor(r.y,  8, 64);
    r.z += __shfl_xor(r.z,  8, 64);
    r.w += __shfl_xor(r.w,  8, 64);
    r.x += __shfl_xor(r.x, 16, 64);
    r.y += __shfl_xor(r.y, 16, 64);
    r.z += __shfl_xor(r.z, 16, 64);
    r.w += __shfl_xor(r.w, 16, 64);
    r.x += __shfl_xor(r.x, 32, 64);
    r.y += __shfl_xor(r.y, 32, 64);
    r.z += __shfl_xor(r.z, 32, 64);
    r.w += __shfl_xor(r.w, 32, 64);
    if (sg == 0) {
        float s = nrm[node];
        r.x *= s; r.y *= s; r.z *= s; r.w *= s;
        *(float4*)&out[(size_t)node * DIM + c] = r;
    }
}

// C[64 x 128] = A[64 x 128] @ W[128 x 128]; A-tile in LDS (32KB, broadcast
// reads), W streamed from L2. Epilogue: relu + nrm[row] prescale.
__global__ __launch_bounds__(256) void gemm_kernel(
        const float* __restrict__ A, const float* __restrict__ W,
        const float* __restrict__ nrm, float* __restrict__ out, int n) {
    __shared__ float As[64 * DIM];
    int t = threadIdx.x;
    int row0 = blockIdx.x * 64;

    for (int q = t; q < 64 * 32; q += 256) {
        int r = q >> 5, c4 = q & 31;
        int row = row0 + r;
        float4 v = (row < n) ? *(const float4*)&A[(size_t)row * DIM + c4 * 4]
                             : make_float4(0.f, 0.f, 0.f, 0.f);
        *(float4*)&As[r * DIM + c4 * 4] = v;
    }
    __syncthreads();

    int tc = t & 31, tr = t >> 5;
    float acc[8][4];
#pragma unroll
    for (int i = 0; i < 8; ++i)
#pragma unroll
        for (int j = 0; j < 4; ++j) acc[i][j] = 0.f;

    for (int k4 = 0; k4 < 32; ++k4) {
        float w[4][4];
#pragma unroll
        for (int dk = 0; dk < 4; ++dk) {
            float4 wv4 = *(const float4*)&W[(size_t)(k4 * 4 + dk) * DIM + tc * 4];
            w[dk][0] = wv4.x; w[dk][1] = wv4.y; w[dk][2] = wv4.z; w[dk][3] = wv4.w;
        }
#pragma unroll
        for (int i = 0; i < 8; ++i) {
            float4 a = *(const float4*)&As[(tr * 8 + i) * DIM + k4 * 4];
            float av[4] = {a.x, a.y, a.z, a.w};
#pragma unroll
            for (int dk = 0; dk < 4; ++dk)
#pragma unroll
                for (int j = 0; j < 4; ++j)
                    acc[i][j] += av[dk] * w[dk][j];
        }
    }

#pragma unroll
    for (int i = 0; i < 8; ++i) {
        int row = row0 + tr * 8 + i;
        if (row >= n) continue;
        float s = nrm[row];
        float4 v = make_float4(acc[i][0], acc[i][1], acc[i][2], acc[i][3]);
        v.x = fmaxf(v.x, 0.f) * s; v.y = fmaxf(v.y, 0.f) * s;
        v.z = fmaxf(v.z, 0.f) * s; v.w = fmaxf(v.w, 0.f) * s;
        *(float4*)&out[(size_t)row * DIM + tc * 4] = v;
    }
}

// Layer-3 GEMM: A[64x128] @ W[128 x outw] -> out zero-PADDED to [n][64].
__global__ __launch_bounds__(256) void gemm3_kernel(
        const float* __restrict__ A, const float* __restrict__ W,
        float* __restrict__ out, int n, int outw) {
    __shared__ float As[64 * DIM];
    int t = threadIdx.x;
    int row0 = blockIdx.x * 64;
    for (int q = t; q < 64 * 32; q += 256) {
        int r = q >> 5, c4 = q & 31;
        int row = row0 + r;
        float4 v = (row < n) ? *(const float4*)&A[(size_t)row * DIM + c4 * 4]
                             : make_float4(0.f, 0.f, 0.f, 0.f);
        *(float4*)&As[r * DIM + c4 * 4] = v;
    }
    __syncthreads();

    int tc = t & 31, tr = t >> 5;
    float acc[8][2];
#pragma unroll
    for (int i = 0; i < 8; ++i) { acc[i][0] = 0.f; acc[i][1] = 0.f; }

    for (int k4 = 0; k4 < 32; ++k4) {
        float w[4][2];
#pragma unroll
        for (int dk = 0; dk < 4; ++dk) {
            int k = k4 * 4 + dk;
            int c0 = tc * 2, c1 = c0 + 1;
            w[dk][0] = (c0 < outw) ? W[(size_t)k * outw + c0] : 0.f;
            w[dk][1] = (c1 < outw) ? W[(size_t)k * outw + c1] : 0.f;
        }
#pragma unroll
        for (int i = 0; i < 8; ++i) {
            float4 a = *(const float4*)&As[(tr * 8 + i) * DIM + k4 * 4];
            float av[4] = {a.x, a.y, a.z, a.w};
#pragma unroll
            for (int dk = 0; dk < 4; ++dk) {
                acc[i][0] += av[dk] * w[dk][0];
                acc[i][1] += av[dk] * w[dk][1];
            }
        }
    }

#pragma unroll
    for (int i = 0; i < 8; ++i) {
        int row = row0 + tr * 8 + i;
        if (row >= n) continue;
        out[(size_t)row * 64 + tc * 2]     = acc[i][0];
        out[(size_t)row * 64 + tc * 2 + 1] = acc[i][1];
    }
}

// Final agg over padded [N][64] rows -> d_out [N][40].
__global__ __launch_bounds__(256) void agg64_kernel(
        const float* __restrict__ hin, const float* __restrict__ nrm,
        const int* __restrict__ off, const int* __restrict__ csr,
        float* __restrict__ out, int N) {
    int t = threadIdx.x;
    int lane = t & 63, wv = t >> 6;
    int node = blockIdx.x * 8 + wv * 2 + (lane >> 5);
    if (node >= N) return;
    int pos = lane & 15, sg = (lane >> 4) & 1;
    int b = off[node], e = off[node + 1];
    float4 a0 = make_float4(0,0,0,0), a1 = a0, a2 = a0, a3 = a0;
    int j = b + sg;
    for (; j + 6 < e; j += 8) {
        int s0 = csr[j], s1 = csr[j+2], s2 = csr[j+4], s3 = csr[j+6];
        float4 v0 = *(const float4*)&hin[(size_t)s0 * 64 + pos * 4];
        float4 v1 = *(const float4*)&hin[(size_t)s1 * 64 + pos * 4];
        float4 v2 = *(const float4*)&hin[(size_t)s2 * 64 + pos * 4];
        float4 v3 = *(const float4*)&hin[(size_t)s3 * 64 + pos * 4];
        a0.x+=v0.x; a0.y+=v0.y; a0.z+=v0.z; a0.w+=v0.w;
        a1.x+=v1.x; a1.y+=v1.y; a1.z+=v1.z; a1.w+=v1.w;
        a2.x+=v2.x; a2.y+=v2.y; a2.z+=v2.z; a2.w+=v2.w;
        a3.x+=v3.x; a3.y+=v3.y; a3.z+=v3.z; a3.w+=v3.w;
    }
    for (; j < e; j += 2) {
        float4 v = *(const float4*)&hin[(size_t)csr[j] * 64 + pos * 4];
        a0.x+=v.x; a0.y+=v.y; a0.z+=v.z; a0.w+=v.w;
    }
    float4 r;
    r.x = (a0.x+a1.x) + (a2.x+a3.x);
    r.y = (a0.y+a1.y) + (a2.y+a3.y);
    r.z = (a0.z+a1.z) + (a2.z+a3.z);
    r.w = (a0.w+a1.w) + (a2.w+a3.w);
    r.x += __shfl_xor(r.x, 16, 64);
    r.y += __shfl_xor(r.y, 16, 64);
    r.z += __shfl_xor(r.z, 16, 64);
    r.w += __shfl_xor(r.w, 16, 64);
    if (sg == 0 && pos < 10) {          // cols 0..39
        float s = nrm[node];
        r.x *= s; r.y *= s; r.z *= s; r.w *= s;
        *(float4*)&out[(size_t)node * 40 + pos * 4] = r;
    }
}

extern "C" void kernel_launch(void* const* d_in, const int* in_sizes, int n_in,
                              void* d_out, int out_size, void* d_ws, size_t ws_size,
                              hipStream_t stream) {
    const float* features = (const float*)d_in[0];
    const int*   edges    = (const int*)d_in[1];
    const float* W0       = (const float*)d_in[2];
    const float* W1       = (const float*)d_in[3];
    const float* W2       = (const float*)d_in[4];
    const float* W3       = (const float*)d_in[5];

    const int N = in_sizes[0] / DIM;       // 50000
    const int E = in_sizes[1] / 2;         // 640000
    const int DOUT = out_size / N;         // 40
    const int* src = edges;
    const int* dst = edges + E;

    char* p = (char*)d_ws;
    float* bufA = (float*)p;  p += (size_t)N * DIM * 4;
    float* bufB = (float*)p;  p += (size_t)N * DIM * 4;
    float* nrm  = (float*)p;  p += (size_t)N * 4;
    int*   deg  = (int*)p;    p += (size_t)N * 4;
    int*   cur  = (int*)p;    p += (size_t)N * 4;   // adjacent to deg -> one memset
    int*   off  = (int*)p;    p += (size_t)(N + 1) * 4;
    int*   bsum = (int*)p;    p += 64 * 4;
    int*   csr  = (int*)p;    p += (size_t)E * 4;
    (void)ws_size; (void)n_in;

    hipMemsetAsync(deg, 0, (size_t)N * 2 * sizeof(int), stream);  // deg + cur

    int eb = (E + 255) / 256;
    int G  = (N + CHUNK - 1) / CHUNK;      // 49
    deg_kernel <<<eb, 256, 0, stream>>>(dst, deg, E);
    scanA_kernel<<<G, 256, 0, stream>>>(deg, nrm, bsum, N);
    scanB_kernel<<<1, 64, 0, stream>>>(bsum, off, G, N);
    scanC_kernel<<<G, 256, 0, stream>>>(deg, bsum, off, N);
    fill_kernel<<<eb, 256, 0, stream>>>(src, dst, off, cur, csr, E);

    int n4 = N * (DIM / 4);
    scale_kernel<<<(n4 + 255) / 256, 256, 0, stream>>>(features, nrm, bufA, n4);

    int gb = (N + 63) / 64;
    int ab = 4 * ((N + 3) / 4);            // 4 chunks x node-groups = 50000
    agg_kernel <<<ab, 256, 0, stream>>>(bufA, nrm, off, csr, bufB, N);
    gemm_kernel<<<gb, 256, 0, stream>>>(bufB, W0, nrm, bufA, N);

    agg_kernel <<<ab, 256, 0, stream>>>(bufA, nrm, off, csr, bufB, N);
    gemm_kernel<<<gb, 256, 0, stream>>>(bufB, W1, nrm, bufA, N);

    agg_kernel <<<ab, 256, 0, stream>>>(bufA, nrm, off, csr, bufB, N);
    gemm_kernel<<<gb, 256, 0, stream>>>(bufB, W2, nrm, bufA, N);

    // layer 3: GEMM first (128->40, padded to 64 cols), then aggregate
    gemm3_kernel<<<gb, 256, 0, stream>>>(bufA, W3, bufB, N, DOUT);
    agg64_kernel<<<(N + 7) / 8, 256, 0, stream>>>(bufB, nrm, off, csr,
                                                  (float*)d_out, N);
}

// Round 8
// 397.717 us; speedup vs baseline: 1.1141x; 1.1141x over previous
//
#include <hip/hip_runtime.h>

// GCN: 4 layers, N=50000, E=640000, d=128 (last 128->40).
// R8: gather is at a ~7 TB/s delivered-BW wall (R3/R6 identical at 46.5us;
// chunking variants R5/R7 worse) -> accept it, fuse agg+GEMM with SMALL tiles
// to keep the grid big (R4's failure was 782 blocks, not fusion): 16-row
// tiles, 3125 blocks, 8KB LDS. GEMM VALU work hides under the BW wall.
// Layer-0 prescale folded into gather (scale_kernel deleted).

#define DIM 128
#define CHUNK 1024        // scan chunk

__global__ void deg_kernel(const int* __restrict__ dst, int* __restrict__ deg, int E) {
    int i = blockIdx.x * blockDim.x + threadIdx.x;
    if (i < E) atomicAdd(&deg[dst[i]], 1);
}

// Phase A: per-chunk sums of deg; also computes nrm = rsqrt(max(deg,1)).
__global__ __launch_bounds__(256) void scanA_kernel(
        const int* __restrict__ deg, float* __restrict__ nrm,
        int* __restrict__ bsum, int n) {
    int b = blockIdx.x, t = threadIdx.x;
    int base = b * CHUNK + t * 4;
    int s = 0;
    if (base + 3 < n) {
        int4 d = *(const int4*)&deg[base];
        s = d.x + d.y + d.z + d.w;
        float4 r;
        r.x = rsqrtf(fmaxf((float)d.x, 1.0f));
        r.y = rsqrtf(fmaxf((float)d.y, 1.0f));
        r.z = rsqrtf(fmaxf((float)d.z, 1.0f));
        r.w = rsqrtf(fmaxf((float)d.w, 1.0f));
        *(float4*)&nrm[base] = r;
    } else {
        for (int j = 0; j < 4; ++j) {
            int idx = base + j;
            if (idx < n) {
                int d = deg[idx];
                s += d;
                nrm[idx] = rsqrtf(fmaxf((float)d, 1.0f));
            }
        }
    }
    for (int o = 32; o; o >>= 1) s += __shfl_down(s, o, 64);
    __shared__ int ws[4];
    if ((t & 63) == 0) ws[t >> 6] = s;
    __syncthreads();
    if (t == 0) bsum[b] = ws[0] + ws[1] + ws[2] + ws[3];
}

// Phase B: exclusive scan of bsum[G] in one wave (G <= 64); writes off[n]=total.
__global__ void scanB_kernel(int* __restrict__ bsum, int* __restrict__ off,
                             int G, int n) {
    int t = threadIdx.x;
    int orig = (t < G) ? bsum[t] : 0;
    int v = orig;
    for (int o = 1; o < 64; o <<= 1) {
        int u = __shfl_up(v, o, 64);
        if (t >= o) v += u;
    }
    if (t < G) bsum[t] = v - orig;
    if (t == G - 1) off[n] = v;
}

// Phase C: off[i] = bsum[chunk] + prefix within chunk. int4 coalesced.
__global__ __launch_bounds__(256) void scanC_kernel(
        const int* __restrict__ deg, const int* __restrict__ bsum,
        int* __restrict__ off, int n) {
    int b = blockIdx.x, t = threadIdx.x;
    int base = b * CHUNK + t * 4;
    int d0 = 0, d1 = 0, d2 = 0, d3 = 0;
    if (base + 3 < n) {
        int4 d = *(const int4*)&deg[base];
        d0 = d.x; d1 = d.y; d2 = d.z; d3 = d.w;
    } else {
        if (base     < n) d0 = deg[base];
        if (base + 1 < n) d1 = deg[base + 1];
        if (base + 2 < n) d2 = deg[base + 2];
    }
    int tot = d0 + d1 + d2 + d3;
    int v = tot;
    for (int o = 1; o < 64; o <<= 1) {
        int u = __shfl_up(v, o, 64);
        if ((t & 63) >= o) v += u;
    }
    __shared__ int wsum[4];
    if ((t & 63) == 63) wsum[t >> 6] = v;
    __syncthreads();
    int wbase = 0;
    for (int w = 0; w < (t >> 6); ++w) wbase += wsum[w];
    int p = bsum[b] + wbase + (v - tot);
    if (base + 3 < n) {
        int4 o4 = make_int4(p, p + d0, p + d0 + d1, p + d0 + d1 + d2);
        *(int4*)&off[base] = o4;
    } else {
        if (base     < n) off[base]     = p;
        if (base + 1 < n) off[base + 1] = p + d0;
        if (base + 2 < n) off[base + 2] = p + d0 + d1;
    }
}

__global__ void fill_kernel(const int* __restrict__ src, const int* __restrict__ dst,
                            const int* __restrict__ off, int* __restrict__ cur,
                            int* __restrict__ csr, int E) {
    int i = blockIdx.x * blockDim.x + threadIdx.x;
    if (i < E) {
        int d = dst[i];
        int p = atomicAdd(&cur[d], 1);
        csr[off[d] + p] = src[i];
    }
}

// Fused layer: 16-row tile. Phase 1: each of 4 waves gathers 4 nodes (R6
// body: float4 half-row, halves on even/odd edges, 4-deep ILP) into LDS.
// Phase 2: C[16x128] = As @ W, relu + nrm[row] prescale, W streamed from L2.
template<bool PRESRC>
__global__ __launch_bounds__(256, 6) void fused_kernel(
        const float* __restrict__ hin, const float* __restrict__ W,
        const float* __restrict__ nrm,
        const int* __restrict__ off, const int* __restrict__ csr,
        float* __restrict__ out, int n) {
    __shared__ float As[16 * DIM];          // 8 KB
    int t = threadIdx.x;
    int lane = t & 63, wv = t >> 6;
    int half = lane >> 5, c = (lane & 31) * 4;
    int row0 = blockIdx.x * 16;

#pragma unroll
    for (int r = 0; r < 4; ++r) {
        int rr = wv * 4 + r;
        int node = row0 + rr;
        int b = 0, e = 0; float s = 0.f;
        if (node < n) { b = off[node]; e = off[node + 1]; s = nrm[node]; }
        float4 a0 = make_float4(0,0,0,0), a1 = a0, a2 = a0, a3 = a0;
        int j = b + half;
        for (; j + 6 < e; j += 8) {
            int s0 = csr[j], s1 = csr[j+2], s2 = csr[j+4], s3 = csr[j+6];
            float4 v0 = *(const float4*)&hin[(size_t)s0 * DIM + c];
            float4 v1 = *(const float4*)&hin[(size_t)s1 * DIM + c];
            float4 v2 = *(const float4*)&hin[(size_t)s2 * DIM + c];
            float4 v3 = *(const float4*)&hin[(size_t)s3 * DIM + c];
            if (PRESRC) {
                float n0 = nrm[s0], n1 = nrm[s1], n2 = nrm[s2], n3 = nrm[s3];
                v0.x*=n0; v0.y*=n0; v0.z*=n0; v0.w*=n0;
                v1.x*=n1; v1.y*=n1; v1.z*=n1; v1.w*=n1;
                v2.x*=n2; v2.y*=n2; v2.z*=n2; v2.w*=n2;
                v3.x*=n3; v3.y*=n3; v3.z*=n3; v3.w*=n3;
            }
            a0.x+=v0.x; a0.y+=v0.y; a0.z+=v0.z; a0.w+=v0.w;
            a1.x+=v1.x; a1.y+=v1.y; a1.z+=v1.z; a1.w+=v1.w;
            a2.x+=v2.x; a2.y+=v2.y; a2.z+=v2.z; a2.w+=v2.w;
            a3.x+=v3.x; a3.y+=v3.y; a3.z+=v3.z; a3.w+=v3.w;
        }
        for (; j < e; j += 2) {
            int s0 = csr[j];
            float4 v = *(const float4*)&hin[(size_t)s0 * DIM + c];
            if (PRESRC) { float nn = nrm[s0]; v.x*=nn; v.y*=nn; v.z*=nn; v.w*=nn; }
            a0.x+=v.x; a0.y+=v.y; a0.z+=v.z; a0.w+=v.w;
        }
        float4 rsum;
        rsum.x = (a0.x+a1.x) + (a2.x+a3.x);
        rsum.y = (a0.y+a1.y) + (a2.y+a3.y);
        rsum.z = (a0.z+a1.z) + (a2.z+a3.z);
        rsum.w = (a0.w+a1.w) + (a2.w+a3.w);
        rsum.x += __shfl_xor(rsum.x, 32, 64);
        rsum.y += __shfl_xor(rsum.y, 32, 64);
        rsum.z += __shfl_xor(rsum.z, 32, 64);
        rsum.w += __shfl_xor(rsum.w, 32, 64);
        if (half == 0) {
            rsum.x *= s; rsum.y *= s; rsum.z *= s; rsum.w *= s;
            *(float4*)&As[rr * DIM + c] = rsum;
        }
    }
    __syncthreads();

    // GEMM: 2 rows x 4 cols per thread. tr = t>>5 (rows tr*2 .. tr*2+1).
    int tc = t & 31, tr = t >> 5;
    float acc[2][4];
#pragma unroll
    for (int i = 0; i < 2; ++i)
#pragma unroll
        for (int j = 0; j < 4; ++j) acc[i][j] = 0.f;

    for (int k4 = 0; k4 < 32; ++k4) {
        float w[4][4];
#pragma unroll
        for (int dk = 0; dk < 4; ++dk) {
            float4 wv4 = *(const float4*)&W[(size_t)(k4 * 4 + dk) * DIM + tc * 4];
            w[dk][0] = wv4.x; w[dk][1] = wv4.y; w[dk][2] = wv4.z; w[dk][3] = wv4.w;
        }
#pragma unroll
        for (int i = 0; i < 2; ++i) {
            float4 a = *(const float4*)&As[(tr * 2 + i) * DIM + k4 * 4];
            float av[4] = {a.x, a.y, a.z, a.w};
#pragma unroll
            for (int dk = 0; dk < 4; ++dk)
#pragma unroll
                for (int j = 0; j < 4; ++j)
                    acc[i][j] += av[dk] * w[dk][j];
        }
    }

#pragma unroll
    for (int i = 0; i < 2; ++i) {
        int row = row0 + tr * 2 + i;
        if (row >= n) continue;
        float s = nrm[row];
        float4 v = make_float4(acc[i][0], acc[i][1], acc[i][2], acc[i][3]);
        v.x = fmaxf(v.x, 0.f) * s; v.y = fmaxf(v.y, 0.f) * s;
        v.z = fmaxf(v.z, 0.f) * s; v.w = fmaxf(v.w, 0.f) * s;
        *(float4*)&out[(size_t)row * DIM + tc * 4] = v;
    }
}

// Layer-3 GEMM: A[64x128] @ W[128 x outw] -> out zero-PADDED to [n][64].
__global__ __launch_bounds__(256) void gemm3_kernel(
        const float* __restrict__ A, const float* __restrict__ W,
        float* __restrict__ out, int n, int outw) {
    __shared__ float As[64 * DIM];
    int t = threadIdx.x;
    int row0 = blockIdx.x * 64;
    for (int q = t; q < 64 * 32; q += 256) {
        int r = q >> 5, c4 = q & 31;
        int row = row0 + r;
        float4 v = (row < n) ? *(const float4*)&A[(size_t)row * DIM + c4 * 4]
                             : make_float4(0.f, 0.f, 0.f, 0.f);
        *(float4*)&As[r * DIM + c4 * 4] = v;
    }
    __syncthreads();

    int tc = t & 31, tr = t >> 5;
    float acc[8][2];
#pragma unroll
    for (int i = 0; i < 8; ++i) { acc[i][0] = 0.f; acc[i][1] = 0.f; }

    for (int k4 = 0; k4 < 32; ++k4) {
        float w[4][2];
#pragma unroll
        for (int dk = 0; dk < 4; ++dk) {
            int k = k4 * 4 + dk;
            int c0 = tc * 2, c1 = c0 + 1;
            w[dk][0] = (c0 < outw) ? W[(size_t)k * outw + c0] : 0.f;
            w[dk][1] = (c1 < outw) ? W[(size_t)k * outw + c1] : 0.f;
        }
#pragma unroll
        for (int i = 0; i < 8; ++i) {
            float4 a = *(const float4*)&As[(tr * 8 + i) * DIM + k4 * 4];
            float av[4] = {a.x, a.y, a.z, a.w};
#pragma unroll
            for (int dk = 0; dk < 4; ++dk) {
                acc[i][0] += av[dk] * w[dk][0];
                acc[i][1] += av[dk] * w[dk][1];
            }
        }
    }

#pragma unroll
    for (int i = 0; i < 8; ++i) {
        int row = row0 + tr * 8 + i;
        if (row >= n) continue;
        out[(size_t)row * 64 + tc * 2]     = acc[i][0];
        out[(size_t)row * 64 + tc * 2 + 1] = acc[i][1];
    }
}

// Final agg over padded [N][64] rows -> d_out [N][40].
__global__ __launch_bounds__(256) void agg64_kernel(
        const float* __restrict__ hin, const float* __restrict__ nrm,
        const int* __restrict__ off, const int* __restrict__ csr,
        float* __restrict__ out, int N) {
    int t = threadIdx.x;
    int lane = t & 63, wv = t >> 6;
    int node = blockIdx.x * 8 + wv * 2 + (lane >> 5);
    if (node >= N) return;
    int pos = lane & 15, sg = (lane >> 4) & 1;
    int b = off[node], e = off[node + 1];
    float4 a0 = make_float4(0,0,0,0), a1 = a0, a2 = a0, a3 = a0;
    int j = b + sg;
    for (; j + 6 < e; j += 8) {
        int s0 = csr[j], s1 = csr[j+2], s2 = csr[j+4], s3 = csr[j+6];
        float4 v0 = *(const float4*)&hin[(size_t)s0 * 64 + pos * 4];
        float4 v1 = *(const float4*)&hin[(size_t)s1 * 64 + pos * 4];
        float4 v2 = *(const float4*)&hin[(size_t)s2 * 64 + pos * 4];
        float4 v3 = *(const float4*)&hin[(size_t)s3 * 64 + pos * 4];
        a0.x+=v0.x; a0.y+=v0.y; a0.z+=v0.z; a0.w+=v0.w;
        a1.x+=v1.x; a1.y+=v1.y; a1.z+=v1.z; a1.w+=v1.w;
        a2.x+=v2.x; a2.y+=v2.y; a2.z+=v2.z; a2.w+=v2.w;
        a3.x+=v3.x; a3.y+=v3.y; a3.z+=v3.z; a3.w+=v3.w;
    }
    for (; j < e; j += 2) {
        float4 v = *(const float4*)&hin[(size_t)csr[j] * 64 + pos * 4];
        a0.x+=v.x; a0.y+=v.y; a0.z+=v.z; a0.w+=v.w;
    }
    float4 r;
    r.x = (a0.x+a1.x) + (a2.x+a3.x);
    r.y = (a0.y+a1.y) + (a2.y+a3.y);
    r.z = (a0.z+a1.z) + (a2.z+a3.z);
    r.w = (a0.w+a1.w) + (a2.w+a3.w);
    r.x += __shfl_xor(r.x, 16, 64);
    r.y += __shfl_xor(r.y, 16, 64);
    r.z += __shfl_xor(r.z, 16, 64);
    r.w += __shfl_xor(r.w, 16, 64);
    if (sg == 0 && pos < 10) {          // cols 0..39
        float s = nrm[node];
        r.x *= s; r.y *= s; r.z *= s; r.w *= s;
        *(float4*)&out[(size_t)node * 40 + pos * 4] = r;
    }
}

extern "C" void kernel_launch(void* const* d_in, const int* in_sizes, int n_in,
                              void* d_out, int out_size, void* d_ws, size_t ws_size,
                              hipStream_t stream) {
    const float* features = (const float*)d_in[0];
    const int*   edges    = (const int*)d_in[1];
    const float* W0       = (const float*)d_in[2];
    const float* W1       = (const float*)d_in[3];
    const float* W2       = (const float*)d_in[4];
    const float* W3       = (const float*)d_in[5];

    const int N = in_sizes[0] / DIM;       // 50000
    const int E = in_sizes[1] / 2;         // 640000
    const int DOUT = out_size / N;         // 40
    const int* src = edges;
    const int* dst = edges + E;

    char* p = (char*)d_ws;
    float* bufA = (float*)p;  p += (size_t)N * DIM * 4;
    float* bufB = (float*)p;  p += (size_t)N * DIM * 4;
    float* nrm  = (float*)p;  p += (size_t)N * 4;
    int*   deg  = (int*)p;    p += (size_t)N * 4;
    int*   cur  = (int*)p;    p += (size_t)N * 4;   // adjacent to deg -> one memset
    int*   off  = (int*)p;    p += (size_t)(N + 1) * 4;
    int*   bsum = (int*)p;    p += 64 * 4;
    int*   csr  = (int*)p;    p += (size_t)E * 4;
    (void)ws_size; (void)n_in;

    hipMemsetAsync(deg, 0, (size_t)N * 2 * sizeof(int), stream);  // deg + cur

    int eb = (E + 255) / 256;
    int G  = (N + CHUNK - 1) / CHUNK;      // 49
    deg_kernel <<<eb, 256, 0, stream>>>(dst, deg, E);
    scanA_kernel<<<G, 256, 0, stream>>>(deg, nrm, bsum, N);
    scanB_kernel<<<1, 64, 0, stream>>>(bsum, off, G, N);
    scanC_kernel<<<G, 256, 0, stream>>>(deg, bsum, off, N);
    fill_kernel<<<eb, 256, 0, stream>>>(src, dst, off, cur, csr, E);

    int fb = (N + 15) / 16;                // 3125 blocks
    int gb = (N + 63) / 64;
    // layers 0..2 fused: gather(+layer0 prescale) -> LDS(8KB) -> GEMM
    fused_kernel<true> <<<fb, 256, 0, stream>>>(features, W0, nrm, off, csr, bufA, N);
    fused_kernel<false><<<fb, 256, 0, stream>>>(bufA, W1, nrm, off, csr, bufB, N);
    fused_kernel<false><<<fb, 256, 0, stream>>>(bufB, W2, nrm, off, csr, bufA, N);

    // layer 3: GEMM first (128->40, padded to 64 cols), then aggregate
    gemm3_kernel<<<gb, 256, 0, stream>>>(bufA, W3, bufB, N, DOUT);
    agg64_kernel<<<(N + 7) / 8, 256, 0, stream>>>(bufB, nrm, off, csr,
                                                  (float*)d_out, N);
}

// Round 9
// 350.537 us; speedup vs baseline: 1.2641x; 1.1346x over previous
//
#include <hip/hip_runtime.h>

// GCN: 4 layers, N=50000, E=640000, d=128 (last 128->40).
// R9: R6 skeleton (proven at the ~7 TB/s gather wall; fusion dead after
// R4/R8). Harvest: scanB merged into scanC (+cur zeroing), feature prescale
// folded into agg0 (scale_kernel deleted), last layer unpadded ([N][40]
// gemm3 + shuffle-free 16-lane-group agg40). 15 -> 13 launches.

#define DIM 128
#define CHUNK 1024        // scan chunk

__global__ void deg_kernel(const int* __restrict__ dst, int* __restrict__ deg, int E) {
    int i = blockIdx.x * blockDim.x + threadIdx.x;
    if (i < E) atomicAdd(&deg[dst[i]], 1);
}

// Phase A: per-chunk sums of deg; also computes nrm = rsqrt(max(deg,1)).
__global__ __launch_bounds__(256) void scanA_kernel(
        const int* __restrict__ deg, float* __restrict__ nrm,
        int* __restrict__ bsum, int n) {
    int b = blockIdx.x, t = threadIdx.x;
    int base = b * CHUNK + t * 4;
    int s = 0;
    if (base + 3 < n) {
        int4 d = *(const int4*)&deg[base];
        s = d.x + d.y + d.z + d.w;
        float4 r;
        r.x = rsqrtf(fmaxf((float)d.x, 1.0f));
        r.y = rsqrtf(fmaxf((float)d.y, 1.0f));
        r.z = rsqrtf(fmaxf((float)d.z, 1.0f));
        r.w = rsqrtf(fmaxf((float)d.w, 1.0f));
        *(float4*)&nrm[base] = r;
    } else {
        for (int j = 0; j < 4; ++j) {
            int idx = base + j;
            if (idx < n) {
                int d = deg[idx];
                s += d;
                nrm[idx] = rsqrtf(fmaxf((float)d, 1.0f));
            }
        }
    }
    for (int o = 32; o; o >>= 1) s += __shfl_down(s, o, 64);
    __shared__ int ws[4];
    if ((t & 63) == 0) ws[t >> 6] = s;
    __syncthreads();
    if (t == 0) bsum[b] = ws[0] + ws[1] + ws[2] + ws[3];
}

// Merged B+C: wave 0 scans bsum[G] in registers (exclusive prefix for this
// block + grand total); all threads zero cur; then per-chunk offsets (int4).
__global__ __launch_bounds__(256) void scanBC_kernel(
        const int* __restrict__ deg, const int* __restrict__ bsum,
        int* __restrict__ off, int* __restrict__ cur, int n, int G) {
    __shared__ int pbs;
    __shared__ int wsum[4];
    int b = blockIdx.x, t = threadIdx.x;
    if (t < 64) {
        int orig = (t < G) ? bsum[t] : 0;
        int v = orig;
        for (int o = 1; o < 64; o <<= 1) {
            int u = __shfl_up(v, o, 64);
            if (t >= o) v += u;
        }
        if (b == 0 && t == G - 1) off[n] = v;   // grand total
        if (t == b) pbs = v - orig;             // exclusive prefix of chunk b
    }
    int base = b * CHUNK + t * 4;
    // zero cur for this chunk (used by fill_kernel)
    if (base + 3 < n) *(int4*)&cur[base] = make_int4(0, 0, 0, 0);
    else for (int j = 0; j < 4; ++j) if (base + j < n) cur[base + j] = 0;

    int d0 = 0, d1 = 0, d2 = 0, d3 = 0;
    if (base + 3 < n) {
        int4 d = *(const int4*)&deg[base];
        d0 = d.x; d1 = d.y; d2 = d.z; d3 = d.w;
    } else {
        if (base     < n) d0 = deg[base];
        if (base + 1 < n) d1 = deg[base + 1];
        if (base + 2 < n) d2 = deg[base + 2];
    }
    int tot = d0 + d1 + d2 + d3;
    int v = tot;
    for (int o = 1; o < 64; o <<= 1) {
        int u = __shfl_up(v, o, 64);
        if ((t & 63) >= o) v += u;
    }
    if ((t & 63) == 63) wsum[t >> 6] = v;
    __syncthreads();
    int wbase = 0;
    for (int w = 0; w < (t >> 6); ++w) wbase += wsum[w];
    int p = pbs + wbase + (v - tot);
    if (base + 3 < n) {
        int4 o4 = make_int4(p, p + d0, p + d0 + d1, p + d0 + d1 + d2);
        *(int4*)&off[base] = o4;
    } else {
        if (base     < n) off[base]     = p;
        if (base + 1 < n) off[base + 1] = p + d0;
        if (base + 2 < n) off[base + 2] = p + d0 + d1;
    }
}

__global__ void fill_kernel(const int* __restrict__ src, const int* __restrict__ dst,
                            const int* __restrict__ off, int* __restrict__ cur,
                            int* __restrict__ csr, int E) {
    int i = blockIdx.x * blockDim.x + threadIdx.x;
    if (i < E) {
        int d = dst[i];
        int p = atomicAdd(&cur[d], 1);
        csr[off[d] + p] = src[i];
    }
}

// One wave per node (R6 body, at the delivered-BW wall). float4 half-row,
// halves on even/odd edges, 4-deep ILP = 8 edge-rows (4KB) in flight/wave.
// PRESRC: multiply each gathered row by nrm[src] (layer 0 reads features).
template<bool PRESRC>
__global__ __launch_bounds__(256) void agg_kernel(
        const float* __restrict__ hin, const float* __restrict__ nrm,
        const int* __restrict__ off, const int* __restrict__ csr,
        float* __restrict__ out, int N) {
    int lane = threadIdx.x & 63;
    int node = blockIdx.x * 4 + (threadIdx.x >> 6);
    if (node >= N) return;
    int half = lane >> 5, c = (lane & 31) * 4;
    int b = off[node], e = off[node + 1];
    float4 a0 = make_float4(0,0,0,0), a1 = a0, a2 = a0, a3 = a0;
    int j = b + half;
    for (; j + 6 < e; j += 8) {
        int s0 = csr[j], s1 = csr[j+2], s2 = csr[j+4], s3 = csr[j+6];
        float4 v0 = *(const float4*)&hin[(size_t)s0 * DIM + c];
        float4 v1 = *(const float4*)&hin[(size_t)s1 * DIM + c];
        float4 v2 = *(const float4*)&hin[(size_t)s2 * DIM + c];
        float4 v3 = *(const float4*)&hin[(size_t)s3 * DIM + c];
        if (PRESRC) {
            float n0 = nrm[s0], n1 = nrm[s1], n2 = nrm[s2], n3 = nrm[s3];
            v0.x*=n0; v0.y*=n0; v0.z*=n0; v0.w*=n0;
            v1.x*=n1; v1.y*=n1; v1.z*=n1; v1.w*=n1;
            v2.x*=n2; v2.y*=n2; v2.z*=n2; v2.w*=n2;
            v3.x*=n3; v3.y*=n3; v3.z*=n3; v3.w*=n3;
        }
        a0.x+=v0.x; a0.y+=v0.y; a0.z+=v0.z; a0.w+=v0.w;
        a1.x+=v1.x; a1.y+=v1.y; a1.z+=v1.z; a1.w+=v1.w;
        a2.x+=v2.x; a2.y+=v2.y; a2.z+=v2.z; a2.w+=v2.w;
        a3.x+=v3.x; a3.y+=v3.y; a3.z+=v3.z; a3.w+=v3.w;
    }
    for (; j < e; j += 2) {
        int s0 = csr[j];
        float4 v = *(const float4*)&hin[(size_t)s0 * DIM + c];
        if (PRESRC) { float nn = nrm[s0]; v.x*=nn; v.y*=nn; v.z*=nn; v.w*=nn; }
        a0.x+=v.x; a0.y+=v.y; a0.z+=v.z; a0.w+=v.w;
    }
    float4 r;
    r.x = (a0.x+a1.x) + (a2.x+a3.x);
    r.y = (a0.y+a1.y) + (a2.y+a3.y);
    r.z = (a0.z+a1.z) + (a2.z+a3.z);
    r.w = (a0.w+a1.w) + (a2.w+a3.w);
    r.x += __shfl_xor(r.x, 32, 64);
    r.y += __shfl_xor(r.y, 32, 64);
    r.z += __shfl_xor(r.z, 32, 64);
    r.w += __shfl_xor(r.w, 32, 64);
    if (half == 0) {
        float s = nrm[node];
        r.x *= s; r.y *= s; r.z *= s; r.w *= s;
        *(float4*)&out[(size_t)node * DIM + c] = r;
    }
}

// C[64 x 128] = A[64 x 128] @ W[128 x 128]; A-tile in LDS (32KB, broadcast
// reads), W streamed from L2. Epilogue: relu + nrm[row] prescale.
__global__ __launch_bounds__(256) void gemm_kernel(
        const float* __restrict__ A, const float* __restrict__ W,
        const float* __restrict__ nrm, float* __restrict__ out, int n) {
    __shared__ float As[64 * DIM];
    int t = threadIdx.x;
    int row0 = blockIdx.x * 64;

    for (int q = t; q < 64 * 32; q += 256) {
        int r = q >> 5, c4 = q & 31;
        int row = row0 + r;
        float4 v = (row < n) ? *(const float4*)&A[(size_t)row * DIM + c4 * 4]
                             : make_float4(0.f, 0.f, 0.f, 0.f);
        *(float4*)&As[r * DIM + c4 * 4] = v;
    }
    __syncthreads();

    int tc = t & 31, tr = t >> 5;
    float acc[8][4];
#pragma unroll
    for (int i = 0; i < 8; ++i)
#pragma unroll
        for (int j = 0; j < 4; ++j) acc[i][j] = 0.f;

    for (int k4 = 0; k4 < 32; ++k4) {
        float w[4][4];
#pragma unroll
        for (int dk = 0; dk < 4; ++dk) {
            float4 wv4 = *(const float4*)&W[(size_t)(k4 * 4 + dk) * DIM + tc * 4];
            w[dk][0] = wv4.x; w[dk][1] = wv4.y; w[dk][2] = wv4.z; w[dk][3] = wv4.w;
        }
#pragma unroll
        for (int i = 0; i < 8; ++i) {
            float4 a = *(const float4*)&As[(tr * 8 + i) * DIM + k4 * 4];
            float av[4] = {a.x, a.y, a.z, a.w};
#pragma unroll
            for (int dk = 0; dk < 4; ++dk)
#pragma unroll
                for (int j = 0; j < 4; ++j)
                    acc[i][j] += av[dk] * w[dk][j];
        }
    }

#pragma unroll
    for (int i = 0; i < 8; ++i) {
        int row = row0 + tr * 8 + i;
        if (row >= n) continue;
        float s = nrm[row];
        float4 v = make_float4(acc[i][0], acc[i][1], acc[i][2], acc[i][3]);
        v.x = fmaxf(v.x, 0.f) * s; v.y = fmaxf(v.y, 0.f) * s;
        v.z = fmaxf(v.z, 0.f) * s; v.w = fmaxf(v.w, 0.f) * s;
        *(float4*)&out[(size_t)row * DIM + tc * 4] = v;
    }
}

// Layer-3 GEMM: A[64x128] @ W3[128x40] -> out [n][40] (unpadded).
// Threads tc<10 own 4 cols each (float4 W loads/stores).
__global__ __launch_bounds__(256) void gemm3_kernel(
        const float* __restrict__ A, const float* __restrict__ W,
        float* __restrict__ out, int n, int outw) {
    __shared__ float As[64 * DIM];
    int t = threadIdx.x;
    int row0 = blockIdx.x * 64;
    for (int q = t; q < 64 * 32; q += 256) {
        int r = q >> 5, c4 = q & 31;
        int row = row0 + r;
        float4 v = (row < n) ? *(const float4*)&A[(size_t)row * DIM + c4 * 4]
                             : make_float4(0.f, 0.f, 0.f, 0.f);
        *(float4*)&As[r * DIM + c4 * 4] = v;
    }
    __syncthreads();

    int tc = t & 31, tr = t >> 5;
    if (tc >= 10) return;                  // 40 cols = 10 x float4
    float acc[8][4];
#pragma unroll
    for (int i = 0; i < 8; ++i)
#pragma unroll
        for (int j = 0; j < 4; ++j) acc[i][j] = 0.f;

    for (int k4 = 0; k4 < 32; ++k4) {
        float w[4][4];
#pragma unroll
        for (int dk = 0; dk < 4; ++dk) {
            float4 wv4 = *(const float4*)&W[(size_t)(k4 * 4 + dk) * outw + tc * 4];
            w[dk][0] = wv4.x; w[dk][1] = wv4.y; w[dk][2] = wv4.z; w[dk][3] = wv4.w;
        }
#pragma unroll
        for (int i = 0; i < 8; ++i) {
            float4 a = *(const float4*)&As[(tr * 8 + i) * DIM + k4 * 4];
            float av[4] = {a.x, a.y, a.z, a.w};
#pragma unroll
            for (int dk = 0; dk < 4; ++dk)
#pragma unroll
                for (int j = 0; j < 4; ++j)
                    acc[i][j] += av[dk] * w[dk][j];
        }
    }

#pragma unroll
    for (int i = 0; i < 8; ++i) {
        int row = row0 + tr * 8 + i;
        if (row >= n) continue;
        *(float4*)&out[(size_t)row * outw + tc * 4] =
            make_float4(acc[i][0], acc[i][1], acc[i][2], acc[i][3]);
    }
}

// Final agg over [N][40] rows -> d_out [N][40]. 16-lane group per node
// (pos<10 active, float4 covers the 160B row), 4-deep edge ILP, no shuffles.
__global__ __launch_bounds__(256) void agg40_kernel(
        const float* __restrict__ hin, const float* __restrict__ nrm,
        const int* __restrict__ off, const int* __restrict__ csr,
        float* __restrict__ out, int N) {
    int t = threadIdx.x;
    int lane = t & 63, wv = t >> 6;
    int g = lane >> 4, pos = lane & 15;
    int node = blockIdx.x * 16 + wv * 4 + g;
    if (node >= N || pos >= 10) return;
    int b = off[node], e = off[node + 1];
    float4 a0 = make_float4(0,0,0,0), a1 = a0, a2 = a0, a3 = a0;
    int j = b;
    for (; j + 3 < e; j += 4) {
        int s0 = csr[j], s1 = csr[j+1], s2 = csr[j+2], s3 = csr[j+3];
        float4 v0 = *(const float4*)&hin[(size_t)s0 * 40 + pos * 4];
        float4 v1 = *(const float4*)&hin[(size_t)s1 * 40 + pos * 4];
        float4 v2 = *(const float4*)&hin[(size_t)s2 * 40 + pos * 4];
        float4 v3 = *(const float4*)&hin[(size_t)s3 * 40 + pos * 4];
        a0.x+=v0.x; a0.y+=v0.y; a0.z+=v0.z; a0.w+=v0.w;
        a1.x+=v1.x; a1.y+=v1.y; a1.z+=v1.z; a1.w+=v1.w;
        a2.x+=v2.x; a2.y+=v2.y; a2.z+=v2.z; a2.w+=v2.w;
        a3.x+=v3.x; a3.y+=v3.y; a3.z+=v3.z; a3.w+=v3.w;
    }
    for (; j < e; ++j) {
        float4 v = *(const float4*)&hin[(size_t)csr[j] * 40 + pos * 4];
        a0.x+=v.x; a0.y+=v.y; a0.z+=v.z; a0.w+=v.w;
    }
    float s = nrm[node];
    float4 r;
    r.x = ((a0.x+a1.x) + (a2.x+a3.x)) * s;
    r.y = ((a0.y+a1.y) + (a2.y+a3.y)) * s;
    r.z = ((a0.z+a1.z) + (a2.z+a3.z)) * s;
    r.w = ((a0.w+a1.w) + (a2.w+a3.w)) * s;
    *(float4*)&out[(size_t)node * 40 + pos * 4] = r;
}

extern "C" void kernel_launch(void* const* d_in, const int* in_sizes, int n_in,
                              void* d_out, int out_size, void* d_ws, size_t ws_size,
                              hipStream_t stream) {
    const float* features = (const float*)d_in[0];
    const int*   edges    = (const int*)d_in[1];
    const float* W0       = (const float*)d_in[2];
    const float* W1       = (const float*)d_in[3];
    const float* W2       = (const float*)d_in[4];
    const float* W3       = (const float*)d_in[5];

    const int N = in_sizes[0] / DIM;       // 50000
    const int E = in_sizes[1] / 2;         // 640000
    const int DOUT = out_size / N;         // 40
    const int* src = edges;
    const int* dst = edges + E;

    char* p = (char*)d_ws;
    float* bufA = (float*)p;  p += (size_t)N * DIM * 4;
    float* bufB = (float*)p;  p += (size_t)N * DIM * 4;
    float* nrm  = (float*)p;  p += (size_t)N * 4;
    int*   deg  = (int*)p;    p += (size_t)N * 4;
    int*   cur  = (int*)p;    p += (size_t)N * 4;
    int*   off  = (int*)p;    p += (size_t)(N + 1) * 4;
    int*   bsum = (int*)p;    p += 64 * 4;
    int*   csr  = (int*)p;    p += (size_t)E * 4;
    (void)ws_size; (void)n_in;

    hipMemsetAsync(deg, 0, (size_t)N * sizeof(int), stream);

    int eb = (E + 255) / 256;
    int G  = (N + CHUNK - 1) / CHUNK;      // 49
    deg_kernel  <<<eb, 256, 0, stream>>>(dst, deg, E);
    scanA_kernel<<<G, 256, 0, stream>>>(deg, nrm, bsum, N);
    scanBC_kernel<<<G, 256, 0, stream>>>(deg, bsum, off, cur, N, G);
    fill_kernel <<<eb, 256, 0, stream>>>(src, dst, off, cur, csr, E);

    int gb = (N + 63) / 64;
    int ab = (N + 3) / 4;
    // layer 0: gather features with nrm[src] prescale folded in
    agg_kernel<true> <<<ab, 256, 0, stream>>>(features, nrm, off, csr, bufB, N);
    gemm_kernel<<<gb, 256, 0, stream>>>(bufB, W0, nrm, bufA, N);

    agg_kernel<false><<<ab, 256, 0, stream>>>(bufA, nrm, off, csr, bufB, N);
    gemm_kernel<<<gb, 256, 0, stream>>>(bufB, W1, nrm, bufA, N);

    agg_kernel<false><<<ab, 256, 0, stream>>>(bufA, nrm, off, csr, bufB, N);
    gemm_kernel<<<gb, 256, 0, stream>>>(bufB, W2, nrm, bufA, N);

    // layer 3: GEMM first (128->40, unpadded), then gather 160B rows
    gemm3_kernel<<<gb, 256, 0, stream>>>(bufA, W3, bufB, N, DOUT);
    agg40_kernel<<<(N + 15) / 16, 256, 0, stream>>>(bufB, nrm, off, csr,
                                                    (float*)d_out, N);
}

// Round 10
// 319.893 us; speedup vs baseline: 1.3851x; 1.0958x over previous
//
#include <hip/hip_runtime.h>
#include <hip/hip_fp16.h>

// GCN: 4 layers, N=50000, E=640000, d=128 (last 128->40).
// R10: single-variable experiment vs R9 — intermediate h1/h2/h3 stored fp16
// (half gather bytes, SAME instruction count), all arithmetic fp32.
// agg0 (fp32 features) is the unchanged control dispatch.
// Flow: agg0(f32)->bufB | gemm0: bufB->bufH(fp16) | agg1: bufH->bufB |
// gemm1 -> bufH | agg2: bufH->bufB | gemm2 -> bufH | gemm3: bufH->bufB[N][40]
// | agg40: bufB -> d_out.

#define DIM 128
#define CHUNK 1024        // scan chunk

__global__ void deg_kernel(const int* __restrict__ dst, int* __restrict__ deg, int E) {
    int i = blockIdx.x * blockDim.x + threadIdx.x;
    if (i < E) atomicAdd(&deg[dst[i]], 1);
}

// Phase A: per-chunk sums of deg; also computes nrm = rsqrt(max(deg,1)).
__global__ __launch_bounds__(256) void scanA_kernel(
        const int* __restrict__ deg, float* __restrict__ nrm,
        int* __restrict__ bsum, int n) {
    int b = blockIdx.x, t = threadIdx.x;
    int base = b * CHUNK + t * 4;
    int s = 0;
    if (base + 3 < n) {
        int4 d = *(const int4*)&deg[base];
        s = d.x + d.y + d.z + d.w;
        float4 r;
        r.x = rsqrtf(fmaxf((float)d.x, 1.0f));
        r.y = rsqrtf(fmaxf((float)d.y, 1.0f));
        r.z = rsqrtf(fmaxf((float)d.z, 1.0f));
        r.w = rsqrtf(fmaxf((float)d.w, 1.0f));
        *(float4*)&nrm[base] = r;
    } else {
        for (int j = 0; j < 4; ++j) {
            int idx = base + j;
            if (idx < n) {
                int d = deg[idx];
                s += d;
                nrm[idx] = rsqrtf(fmaxf((float)d, 1.0f));
            }
        }
    }
    for (int o = 32; o; o >>= 1) s += __shfl_down(s, o, 64);
    __shared__ int ws[4];
    if ((t & 63) == 0) ws[t >> 6] = s;
    __syncthreads();
    if (t == 0) bsum[b] = ws[0] + ws[1] + ws[2] + ws[3];
}

// Merged B+C: wave 0 scans bsum[G] in registers; zero cur; per-chunk offsets.
__global__ __launch_bounds__(256) void scanBC_kernel(
        const int* __restrict__ deg, const int* __restrict__ bsum,
        int* __restrict__ off, int* __restrict__ cur, int n, int G) {
    __shared__ int pbs;
    __shared__ int wsum[4];
    int b = blockIdx.x, t = threadIdx.x;
    if (t < 64) {
        int orig = (t < G) ? bsum[t] : 0;
        int v = orig;
        for (int o = 1; o < 64; o <<= 1) {
            int u = __shfl_up(v, o, 64);
            if (t >= o) v += u;
        }
        if (b == 0 && t == G - 1) off[n] = v;   // grand total
        if (t == b) pbs = v - orig;             // exclusive prefix of chunk b
    }
    int base = b * CHUNK + t * 4;
    if (base + 3 < n) *(int4*)&cur[base] = make_int4(0, 0, 0, 0);
    else for (int j = 0; j < 4; ++j) if (base + j < n) cur[base + j] = 0;

    int d0 = 0, d1 = 0, d2 = 0, d3 = 0;
    if (base + 3 < n) {
        int4 d = *(const int4*)&deg[base];
        d0 = d.x; d1 = d.y; d2 = d.z; d3 = d.w;
    } else {
        if (base     < n) d0 = deg[base];
        if (base + 1 < n) d1 = deg[base + 1];
        if (base + 2 < n) d2 = deg[base + 2];
    }
    int tot = d0 + d1 + d2 + d3;
    int v = tot;
    for (int o = 1; o < 64; o <<= 1) {
        int u = __shfl_up(v, o, 64);
        if ((t & 63) >= o) v += u;
    }
    if ((t & 63) == 63) wsum[t >> 6] = v;
    __syncthreads();
    int wbase = 0;
    for (int w = 0; w < (t >> 6); ++w) wbase += wsum[w];
    int p = pbs + wbase + (v - tot);
    if (base + 3 < n) {
        int4 o4 = make_int4(p, p + d0, p + d0 + d1, p + d0 + d1 + d2);
        *(int4*)&off[base] = o4;
    } else {
        if (base     < n) off[base]     = p;
        if (base + 1 < n) off[base + 1] = p + d0;
        if (base + 2 < n) off[base + 2] = p + d0 + d1;
    }
}

__global__ void fill_kernel(const int* __restrict__ src, const int* __restrict__ dst,
                            const int* __restrict__ off, int* __restrict__ cur,
                            int* __restrict__ csr, int E) {
    int i = blockIdx.x * blockDim.x + threadIdx.x;
    if (i < E) {
        int d = dst[i];
        int p = atomicAdd(&cur[d], 1);
        csr[off[d] + p] = src[i];
    }
}

// Layer-0 agg (CONTROL, unchanged from R9): fp32 features, nrm[src] prescale.
__global__ __launch_bounds__(256) void agg0_kernel(
        const float* __restrict__ hin, const float* __restrict__ nrm,
        const int* __restrict__ off, const int* __restrict__ csr,
        float* __restrict__ out, int N) {
    int lane = threadIdx.x & 63;
    int node = blockIdx.x * 4 + (threadIdx.x >> 6);
    if (node >= N) return;
    int half = lane >> 5, c = (lane & 31) * 4;
    int b = off[node], e = off[node + 1];
    float4 a0 = make_float4(0,0,0,0), a1 = a0, a2 = a0, a3 = a0;
    int j = b + half;
    for (; j + 6 < e; j += 8) {
        int s0 = csr[j], s1 = csr[j+2], s2 = csr[j+4], s3 = csr[j+6];
        float4 v0 = *(const float4*)&hin[(size_t)s0 * DIM + c];
        float4 v1 = *(const float4*)&hin[(size_t)s1 * DIM + c];
        float4 v2 = *(const float4*)&hin[(size_t)s2 * DIM + c];
        float4 v3 = *(const float4*)&hin[(size_t)s3 * DIM + c];
        float n0 = nrm[s0], n1 = nrm[s1], n2 = nrm[s2], n3 = nrm[s3];
        a0.x+=v0.x*n0; a0.y+=v0.y*n0; a0.z+=v0.z*n0; a0.w+=v0.w*n0;
        a1.x+=v1.x*n1; a1.y+=v1.y*n1; a1.z+=v1.z*n1; a1.w+=v1.w*n1;
        a2.x+=v2.x*n2; a2.y+=v2.y*n2; a2.z+=v2.z*n2; a2.w+=v2.w*n2;
        a3.x+=v3.x*n3; a3.y+=v3.y*n3; a3.z+=v3.z*n3; a3.w+=v3.w*n3;
    }
    for (; j < e; j += 2) {
        int s0 = csr[j];
        float4 v = *(const float4*)&hin[(size_t)s0 * DIM + c];
        float nn = nrm[s0];
        a0.x+=v.x*nn; a0.y+=v.y*nn; a0.z+=v.z*nn; a0.w+=v.w*nn;
    }
    float4 r;
    r.x = (a0.x+a1.x) + (a2.x+a3.x);
    r.y = (a0.y+a1.y) + (a2.y+a3.y);
    r.z = (a0.z+a1.z) + (a2.z+a3.z);
    r.w = (a0.w+a1.w) + (a2.w+a3.w);
    r.x += __shfl_xor(r.x, 32, 64);
    r.y += __shfl_xor(r.y, 32, 64);
    r.z += __shfl_xor(r.z, 32, 64);
    r.w += __shfl_xor(r.w, 32, 64);
    if (half == 0) {
        float s = nrm[node];
        r.x *= s; r.y *= s; r.z *= s; r.w *= s;
        *(float4*)&out[(size_t)node * DIM + c] = r;
    }
}

// fp16-input agg (layers 1,2): same structure, 8B loads (4 halves) per row
// per lane — instruction count identical to agg0, bytes halved. fp32 sums.
__global__ __launch_bounds__(256) void aggh_kernel(
        const __half* __restrict__ hin, const float* __restrict__ nrm,
        const int* __restrict__ off, const int* __restrict__ csr,
        float* __restrict__ out, int N) {
    int lane = threadIdx.x & 63;
    int node = blockIdx.x * 4 + (threadIdx.x >> 6);
    if (node >= N) return;
    int half = lane >> 5, c = (lane & 31) * 4;
    int b = off[node], e = off[node + 1];
    float4 a0 = make_float4(0,0,0,0), a1 = a0, a2 = a0, a3 = a0;
    int j = b + half;
    for (; j + 6 < e; j += 8) {
        int s0 = csr[j], s1 = csr[j+2], s2 = csr[j+4], s3 = csr[j+6];
        uint2 u0 = *(const uint2*)&hin[(size_t)s0 * DIM + c];
        uint2 u1 = *(const uint2*)&hin[(size_t)s1 * DIM + c];
        uint2 u2 = *(const uint2*)&hin[(size_t)s2 * DIM + c];
        uint2 u3 = *(const uint2*)&hin[(size_t)s3 * DIM + c];
        float2 f;
        f = __half22float2(*(__half2*)&u0.x); a0.x += f.x; a0.y += f.y;
        f = __half22float2(*(__half2*)&u0.y); a0.z += f.x; a0.w += f.y;
        f = __half22float2(*(__half2*)&u1.x); a1.x += f.x; a1.y += f.y;
        f = __half22float2(*(__half2*)&u1.y); a1.z += f.x; a1.w += f.y;
        f = __half22float2(*(__half2*)&u2.x); a2.x += f.x; a2.y += f.y;
        f = __half22float2(*(__half2*)&u2.y); a2.z += f.x; a2.w += f.y;
        f = __half22float2(*(__half2*)&u3.x); a3.x += f.x; a3.y += f.y;
        f = __half22float2(*(__half2*)&u3.y); a3.z += f.x; a3.w += f.y;
    }
    for (; j < e; j += 2) {
        uint2 u = *(const uint2*)&hin[(size_t)csr[j] * DIM + c];
        float2 f;
        f = __half22float2(*(__half2*)&u.x); a0.x += f.x; a0.y += f.y;
        f = __half22float2(*(__half2*)&u.y); a0.z += f.x; a0.w += f.y;
    }
    float4 r;
    r.x = (a0.x+a1.x) + (a2.x+a3.x);
    r.y = (a0.y+a1.y) + (a2.y+a3.y);
    r.z = (a0.z+a1.z) + (a2.z+a3.z);
    r.w = (a0.w+a1.w) + (a2.w+a3.w);
    r.x += __shfl_xor(r.x, 32, 64);
    r.y += __shfl_xor(r.y, 32, 64);
    r.z += __shfl_xor(r.z, 32, 64);
    r.w += __shfl_xor(r.w, 32, 64);
    if (half == 0) {
        float s = nrm[node];
        r.x *= s; r.y *= s; r.z *= s; r.w *= s;
        *(float4*)&out[(size_t)node * DIM + c] = r;
    }
}

// C[64 x 128] = A[64 x 128] @ W[128 x 128]; A-tile LDS, W from L2.
// Epilogue: relu + nrm[row] prescale, packed to fp16 (h for the next gather).
__global__ __launch_bounds__(256) void gemm_kernel(
        const float* __restrict__ A, const float* __restrict__ W,
        const float* __restrict__ nrm, __half* __restrict__ outh, int n) {
    __shared__ float As[64 * DIM];
    int t = threadIdx.x;
    int row0 = blockIdx.x * 64;

    for (int q = t; q < 64 * 32; q += 256) {
        int r = q >> 5, c4 = q & 31;
        int row = row0 + r;
        float4 v = (row < n) ? *(const float4*)&A[(size_t)row * DIM + c4 * 4]
                             : make_float4(0.f, 0.f, 0.f, 0.f);
        *(float4*)&As[r * DIM + c4 * 4] = v;
    }
    __syncthreads();

    int tc = t & 31, tr = t >> 5;
    float acc[8][4];
#pragma unroll
    for (int i = 0; i < 8; ++i)
#pragma unroll
        for (int j = 0; j < 4; ++j) acc[i][j] = 0.f;

    for (int k4 = 0; k4 < 32; ++k4) {
        float w[4][4];
#pragma unroll
        for (int dk = 0; dk < 4; ++dk) {
            float4 wv4 = *(const float4*)&W[(size_t)(k4 * 4 + dk) * DIM + tc * 4];
            w[dk][0] = wv4.x; w[dk][1] = wv4.y; w[dk][2] = wv4.z; w[dk][3] = wv4.w;
        }
#pragma unroll
        for (int i = 0; i < 8; ++i) {
            float4 a = *(const float4*)&As[(tr * 8 + i) * DIM + k4 * 4];
            float av[4] = {a.x, a.y, a.z, a.w};
#pragma unroll
            for (int dk = 0; dk < 4; ++dk)
#pragma unroll
                for (int j = 0; j < 4; ++j)
                    acc[i][j] += av[dk] * w[dk][j];
        }
    }

#pragma unroll
    for (int i = 0; i < 8; ++i) {
        int row = row0 + tr * 8 + i;
        if (row >= n) continue;
        float s = nrm[row];
        float4 v = make_float4(acc[i][0], acc[i][1], acc[i][2], acc[i][3]);
        v.x = fmaxf(v.x, 0.f) * s; v.y = fmaxf(v.y, 0.f) * s;
        v.z = fmaxf(v.z, 0.f) * s; v.w = fmaxf(v.w, 0.f) * s;
        __half2 lo = __float22half2_rn(make_float2(v.x, v.y));
        __half2 hi = __float22half2_rn(make_float2(v.z, v.w));
        uint2 u;
        u.x = *(unsigned int*)&lo;
        u.y = *(unsigned int*)&hi;
        *(uint2*)&outh[(size_t)row * DIM + tc * 4] = u;
    }
}

// Layer-3 GEMM: fp16 A[64x128] @ fp32 W3[128x40] -> fp32 out [n][40].
__global__ __launch_bounds__(256) void gemm3_kernel(
        const __half* __restrict__ Ah, const float* __restrict__ W,
        float* __restrict__ out, int n, int outw) {
    __shared__ float As[64 * DIM];
    int t = threadIdx.x;
    int row0 = blockIdx.x * 64;
    for (int q = t; q < 64 * 32; q += 256) {
        int r = q >> 5, c4 = q & 31;
        int row = row0 + r;
        float4 v = make_float4(0.f, 0.f, 0.f, 0.f);
        if (row < n) {
            uint2 u = *(const uint2*)&Ah[(size_t)row * DIM + c4 * 4];
            float2 f0 = __half22float2(*(__half2*)&u.x);
            float2 f1 = __half22float2(*(__half2*)&u.y);
            v = make_float4(f0.x, f0.y, f1.x, f1.y);
        }
        *(float4*)&As[r * DIM + c4 * 4] = v;
    }
    __syncthreads();

    int tc = t & 31, tr = t >> 5;
    if (tc >= 10) return;                  // 40 cols = 10 x float4
    float acc[8][4];
#pragma unroll
    for (int i = 0; i < 8; ++i)
#pragma unroll
        for (int j = 0; j < 4; ++j) acc[i][j] = 0.f;

    for (int k4 = 0; k4 < 32; ++k4) {
        float w[4][4];
#pragma unroll
        for (int dk = 0; dk < 4; ++dk) {
            float4 wv4 = *(const float4*)&W[(size_t)(k4 * 4 + dk) * outw + tc * 4];
            w[dk][0] = wv4.x; w[dk][1] = wv4.y; w[dk][2] = wv4.z; w[dk][3] = wv4.w;
        }
#pragma unroll
        for (int i = 0; i < 8; ++i) {
            float4 a = *(const float4*)&As[(tr * 8 + i) * DIM + k4 * 4];
            float av[4] = {a.x, a.y, a.z, a.w};
#pragma unroll
            for (int dk = 0; dk < 4; ++dk)
#pragma unroll
                for (int j = 0; j < 4; ++j)
                    acc[i][j] += av[dk] * w[dk][j];
        }
    }

#pragma unroll
    for (int i = 0; i < 8; ++i) {
        int row = row0 + tr * 8 + i;
        if (row >= n) continue;
        *(float4*)&out[(size_t)row * outw + tc * 4] =
            make_float4(acc[i][0], acc[i][1], acc[i][2], acc[i][3]);
    }
}

// Final agg over fp32 [N][40] rows -> d_out [N][40]. 16-lane group per node.
__global__ __launch_bounds__(256) void agg40_kernel(
        const float* __restrict__ hin, const float* __restrict__ nrm,
        const int* __restrict__ off, const int* __restrict__ csr,
        float* __restrict__ out, int N) {
    int t = threadIdx.x;
    int lane = t & 63, wv = t >> 6;
    int g = lane >> 4, pos = lane & 15;
    int node = blockIdx.x * 16 + wv * 4 + g;
    if (node >= N || pos >= 10) return;
    int b = off[node], e = off[node + 1];
    float4 a0 = make_float4(0,0,0,0), a1 = a0, a2 = a0, a3 = a0;
    int j = b;
    for (; j + 3 < e; j += 4) {
        int s0 = csr[j], s1 = csr[j+1], s2 = csr[j+2], s3 = csr[j+3];
        float4 v0 = *(const float4*)&hin[(size_t)s0 * 40 + pos * 4];
        float4 v1 = *(const float4*)&hin[(size_t)s1 * 40 + pos * 4];
        float4 v2 = *(const float4*)&hin[(size_t)s2 * 40 + pos * 4];
        float4 v3 = *(const float4*)&hin[(size_t)s3 * 40 + pos * 4];
        a0.x+=v0.x; a0.y+=v0.y; a0.z+=v0.z; a0.w+=v0.w;
        a1.x+=v1.x; a1.y+=v1.y; a1.z+=v1.z; a1.w+=v1.w;
        a2.x+=v2.x; a2.y+=v2.y; a2.z+=v2.z; a2.w+=v2.w;
        a3.x+=v3.x; a3.y+=v3.y; a3.z+=v3.z; a3.w+=v3.w;
    }
    for (; j < e; ++j) {
        float4 v = *(const float4*)&hin[(size_t)csr[j] * 40 + pos * 4];
        a0.x+=v.x; a0.y+=v.y; a0.z+=v.z; a0.w+=v.w;
    }
    float s = nrm[node];
    float4 r;
    r.x = ((a0.x+a1.x) + (a2.x+a3.x)) * s;
    r.y = ((a0.y+a1.y) + (a2.y+a3.y)) * s;
    r.z = ((a0.z+a1.z) + (a2.z+a3.z)) * s;
    r.w = ((a0.w+a1.w) + (a2.w+a3.w)) * s;
    *(float4*)&out[(size_t)node * 40 + pos * 4] = r;
}

extern "C" void kernel_launch(void* const* d_in, const int* in_sizes, int n_in,
                              void* d_out, int out_size, void* d_ws, size_t ws_size,
                              hipStream_t stream) {
    const float* features = (const float*)d_in[0];
    const int*   edges    = (const int*)d_in[1];
    const float* W0       = (const float*)d_in[2];
    const float* W1       = (const float*)d_in[3];
    const float* W2       = (const float*)d_in[4];
    const float* W3       = (const float*)d_in[5];

    const int N = in_sizes[0] / DIM;       // 50000
    const int E = in_sizes[1] / 2;         // 640000
    const int DOUT = out_size / N;         // 40
    const int* src = edges;
    const int* dst = edges + E;

    char* p = (char*)d_ws;
    float*  bufB = (float*)p;  p += (size_t)N * DIM * 4;   // fp32 agg out / gemm3 out
    __half* bufH = (__half*)p; p += (size_t)N * DIM * 2;   // fp16 h1/h2/h3
    float*  nrm  = (float*)p;  p += (size_t)N * 4;
    int*    deg  = (int*)p;    p += (size_t)N * 4;
    int*    cur  = (int*)p;    p += (size_t)N * 4;
    int*    off  = (int*)p;    p += (size_t)(N + 1) * 4;
    int*    bsum = (int*)p;    p += 64 * 4;
    int*    csr  = (int*)p;    p += (size_t)E * 4;
    (void)ws_size; (void)n_in;

    hipMemsetAsync(deg, 0, (size_t)N * sizeof(int), stream);

    int eb = (E + 255) / 256;
    int G  = (N + CHUNK - 1) / CHUNK;      // 49
    deg_kernel   <<<eb, 256, 0, stream>>>(dst, deg, E);
    scanA_kernel <<<G, 256, 0, stream>>>(deg, nrm, bsum, N);
    scanBC_kernel<<<G, 256, 0, stream>>>(deg, bsum, off, cur, N, G);
    fill_kernel  <<<eb, 256, 0, stream>>>(src, dst, off, cur, csr, E);

    int gb = (N + 63) / 64;
    int ab = (N + 3) / 4;
    // layer 0: fp32 features gather (control), gemm -> fp16 h1
    agg0_kernel<<<ab, 256, 0, stream>>>(features, nrm, off, csr, bufB, N);
    gemm_kernel<<<gb, 256, 0, stream>>>(bufB, W0, nrm, bufH, N);

    aggh_kernel<<<ab, 256, 0, stream>>>(bufH, nrm, off, csr, bufB, N);
    gemm_kernel<<<gb, 256, 0, stream>>>(bufB, W1, nrm, bufH, N);

    aggh_kernel<<<ab, 256, 0, stream>>>(bufH, nrm, off, csr, bufB, N);
    gemm_kernel<<<gb, 256, 0, stream>>>(bufB, W2, nrm, bufH, N);

    // layer 3: fp16 A GEMM (128->40, fp32 out), then gather 160B rows
    gemm3_kernel<<<gb, 256, 0, stream>>>(bufH, W3, bufB, N, DOUT);
    agg40_kernel<<<(N + 15) / 16, 256, 0, stream>>>(bufB, nrm, off, csr,
                                                    (float*)d_out, N);
}

// Round 11
// 298.333 us; speedup vs baseline: 1.4853x; 1.0723x over previous
//
#include <hip/hip_runtime.h>
#include <hip/hip_fp16.h>

// GCN: 4 layers, N=50000, E=640000, d=128 (last 128->40).
// R11: full fp16 storage for ALL edge-phase buffers (arithmetic stays fp32):
// featH = features*nrm (fp16, prescaled) -> one agg kernel for all 3 gather
// layers: quarter-wave per edge (16 lanes x uint4 = 256B row, 4 edge
// slots/wave) -> fp16 out. GEMMs read fp16 A, write fp16. Last layer:
// gemm3 -> fp16 [N][40], agg40 gathers 80B rows -> fp32 d_out.

#define DIM 128
#define CHUNK 1024        // scan chunk

__global__ void deg_kernel(const int* __restrict__ dst, int* __restrict__ deg, int E) {
    int i = blockIdx.x * blockDim.x + threadIdx.x;
    if (i < E) atomicAdd(&deg[dst[i]], 1);
}

// Phase A: per-chunk sums of deg; also computes nrm = rsqrt(max(deg,1)).
__global__ __launch_bounds__(256) void scanA_kernel(
        const int* __restrict__ deg, float* __restrict__ nrm,
        int* __restrict__ bsum, int n) {
    int b = blockIdx.x, t = threadIdx.x;
    int base = b * CHUNK + t * 4;
    int s = 0;
    if (base + 3 < n) {
        int4 d = *(const int4*)&deg[base];
        s = d.x + d.y + d.z + d.w;
        float4 r;
        r.x = rsqrtf(fmaxf((float)d.x, 1.0f));
        r.y = rsqrtf(fmaxf((float)d.y, 1.0f));
        r.z = rsqrtf(fmaxf((float)d.z, 1.0f));
        r.w = rsqrtf(fmaxf((float)d.w, 1.0f));
        *(float4*)&nrm[base] = r;
    } else {
        for (int j = 0; j < 4; ++j) {
            int idx = base + j;
            if (idx < n) {
                int d = deg[idx];
                s += d;
                nrm[idx] = rsqrtf(fmaxf((float)d, 1.0f));
            }
        }
    }
    for (int o = 32; o; o >>= 1) s += __shfl_down(s, o, 64);
    __shared__ int ws[4];
    if ((t & 63) == 0) ws[t >> 6] = s;
    __syncthreads();
    if (t == 0) bsum[b] = ws[0] + ws[1] + ws[2] + ws[3];
}

// Merged B+C: wave 0 scans bsum[G] in registers; zero cur; per-chunk offsets.
__global__ __launch_bounds__(256) void scanBC_kernel(
        const int* __restrict__ deg, const int* __restrict__ bsum,
        int* __restrict__ off, int* __restrict__ cur, int n, int G) {
    __shared__ int pbs;
    __shared__ int wsum[4];
    int b = blockIdx.x, t = threadIdx.x;
    if (t < 64) {
        int orig = (t < G) ? bsum[t] : 0;
        int v = orig;
        for (int o = 1; o < 64; o <<= 1) {
            int u = __shfl_up(v, o, 64);
            if (t >= o) v += u;
        }
        if (b == 0 && t == G - 1) off[n] = v;   // grand total
        if (t == b) pbs = v - orig;             // exclusive prefix of chunk b
    }
    int base = b * CHUNK + t * 4;
    if (base + 3 < n) *(int4*)&cur[base] = make_int4(0, 0, 0, 0);
    else for (int j = 0; j < 4; ++j) if (base + j < n) cur[base + j] = 0;

    int d0 = 0, d1 = 0, d2 = 0, d3 = 0;
    if (base + 3 < n) {
        int4 d = *(const int4*)&deg[base];
        d0 = d.x; d1 = d.y; d2 = d.z; d3 = d.w;
    } else {
        if (base     < n) d0 = deg[base];
        if (base + 1 < n) d1 = deg[base + 1];
        if (base + 2 < n) d2 = deg[base + 2];
    }
    int tot = d0 + d1 + d2 + d3;
    int v = tot;
    for (int o = 1; o < 64; o <<= 1) {
        int u = __shfl_up(v, o, 64);
        if ((t & 63) >= o) v += u;
    }
    if ((t & 63) == 63) wsum[t >> 6] = v;
    __syncthreads();
    int wbase = 0;
    for (int w = 0; w < (t >> 6); ++w) wbase += wsum[w];
    int p = pbs + wbase + (v - tot);
    if (base + 3 < n) {
        int4 o4 = make_int4(p, p + d0, p + d0 + d1, p + d0 + d1 + d2);
        *(int4*)&off[base] = o4;
    } else {
        if (base     < n) off[base]     = p;
        if (base + 1 < n) off[base + 1] = p + d0;
        if (base + 2 < n) off[base + 2] = p + d0 + d1;
    }
}

__global__ void fill_kernel(const int* __restrict__ src, const int* __restrict__ dst,
                            const int* __restrict__ off, int* __restrict__ cur,
                            int* __restrict__ csr, int E) {
    int i = blockIdx.x * blockDim.x + threadIdx.x;
    if (i < E) {
        int d = dst[i];
        int p = atomicAdd(&cur[d], 1);
        csr[off[d] + p] = src[i];
    }
}

// featH[r] = features[r] * nrm[r], fp16. i over N*32 float4-groups.
__global__ void conv_kernel(const float* __restrict__ f, const float* __restrict__ nrm,
                            __half* __restrict__ out, int n4) {
    int i = blockIdx.x * blockDim.x + threadIdx.x;
    if (i < n4) {
        int r = i >> 5, c4 = i & 31;
        float s = nrm[r];
        float4 v = ((const float4*)f)[i];
        __half2 lo = __float22half2_rn(make_float2(v.x * s, v.y * s));
        __half2 hi = __float22half2_rn(make_float2(v.z * s, v.w * s));
        uint2 u;
        u.x = *(unsigned int*)&lo;
        u.y = *(unsigned int*)&hi;
        *(uint2*)&out[(size_t)r * DIM + c4 * 4] = u;
    }
}

// fp16 gather, one wave per node. Quarter-wave per edge: pos = lane&15
// (16 lanes x uint4 = 256B row = 2 lines), sg = lane>>4 (4 edge slots),
// 2-deep unroll -> up to 8 edges / 2KB in flight per wave. fp32 sums;
// nrm[node]*sum stored fp16.
__global__ __launch_bounds__(256) void aggh_kernel(
        const __half* __restrict__ hin, const float* __restrict__ nrm,
        const int* __restrict__ off, const int* __restrict__ csr,
        __half* __restrict__ out, int N) {
    int t = threadIdx.x;
    int lane = t & 63;
    int node = blockIdx.x * 4 + (t >> 6);
    if (node >= N) return;
    int pos = lane & 15, sg = lane >> 4;
    int c = pos * 8;                       // half-index within 128-row
    int b = off[node], e = off[node + 1];
    float a[8] = {0,0,0,0,0,0,0,0};
    float bb[8] = {0,0,0,0,0,0,0,0};
    int j = b + sg;
    for (; j + 4 < e; j += 8) {            // 2 edges per slot per iter
        int s0 = csr[j], s1 = csr[j + 4];
        uint4 u0 = *(const uint4*)&hin[(size_t)s0 * DIM + c];
        uint4 u1 = *(const uint4*)&hin[(size_t)s1 * DIM + c];
        float2 f;
        f = __half22float2(*(__half2*)&u0.x); a[0]+=f.x; a[1]+=f.y;
        f = __half22float2(*(__half2*)&u0.y); a[2]+=f.x; a[3]+=f.y;
        f = __half22float2(*(__half2*)&u0.z); a[4]+=f.x; a[5]+=f.y;
        f = __half22float2(*(__half2*)&u0.w); a[6]+=f.x; a[7]+=f.y;
        f = __half22float2(*(__half2*)&u1.x); bb[0]+=f.x; bb[1]+=f.y;
        f = __half22float2(*(__half2*)&u1.y); bb[2]+=f.x; bb[3]+=f.y;
        f = __half22float2(*(__half2*)&u1.z); bb[4]+=f.x; bb[5]+=f.y;
        f = __half22float2(*(__half2*)&u1.w); bb[6]+=f.x; bb[7]+=f.y;
    }
    for (; j < e; j += 4) {
        uint4 u = *(const uint4*)&hin[(size_t)csr[j] * DIM + c];
        float2 f;
        f = __half22float2(*(__half2*)&u.x); a[0]+=f.x; a[1]+=f.y;
        f = __half22float2(*(__half2*)&u.y); a[2]+=f.x; a[3]+=f.y;
        f = __half22float2(*(__half2*)&u.z); a[4]+=f.x; a[5]+=f.y;
        f = __half22float2(*(__half2*)&u.w); a[6]+=f.x; a[7]+=f.y;
    }
#pragma unroll
    for (int k = 0; k < 8; ++k) a[k] += bb[k];
#pragma unroll
    for (int k = 0; k < 8; ++k) {
        a[k] += __shfl_xor(a[k], 16, 64);
        a[k] += __shfl_xor(a[k], 32, 64);
    }
    if (sg == 0) {
        float s = nrm[node];
        __half2 h0 = __float22half2_rn(make_float2(a[0]*s, a[1]*s));
        __half2 h1 = __float22half2_rn(make_float2(a[2]*s, a[3]*s));
        __half2 h2 = __float22half2_rn(make_float2(a[4]*s, a[5]*s));
        __half2 h3 = __float22half2_rn(make_float2(a[6]*s, a[7]*s));
        uint4 u;
        u.x = *(unsigned int*)&h0; u.y = *(unsigned int*)&h1;
        u.z = *(unsigned int*)&h2; u.w = *(unsigned int*)&h3;
        *(uint4*)&out[(size_t)node * DIM + c] = u;
    }
}

// C[64 x 128] = A(fp16)[64 x 128] @ W[128 x 128]; A converted to fp32 LDS.
// Epilogue: relu + nrm[row] prescale, packed fp16.
__global__ __launch_bounds__(256) void gemm_kernel(
        const __half* __restrict__ Ah, const float* __restrict__ W,
        const float* __restrict__ nrm, __half* __restrict__ outh, int n) {
    __shared__ float As[64 * DIM];
    int t = threadIdx.x;
    int row0 = blockIdx.x * 64;

    for (int q = t; q < 64 * 32; q += 256) {
        int r = q >> 5, c4 = q & 31;
        int row = row0 + r;
        float4 v = make_float4(0.f, 0.f, 0.f, 0.f);
        if (row < n) {
            uint2 u = *(const uint2*)&Ah[(size_t)row * DIM + c4 * 4];
            float2 f0 = __half22float2(*(__half2*)&u.x);
            float2 f1 = __half22float2(*(__half2*)&u.y);
            v = make_float4(f0.x, f0.y, f1.x, f1.y);
        }
        *(float4*)&As[r * DIM + c4 * 4] = v;
    }
    __syncthreads();

    int tc = t & 31, tr = t >> 5;
    float acc[8][4];
#pragma unroll
    for (int i = 0; i < 8; ++i)
#pragma unroll
        for (int j = 0; j < 4; ++j) acc[i][j] = 0.f;

    for (int k4 = 0; k4 < 32; ++k4) {
        float w[4][4];
#pragma unroll
        for (int dk = 0; dk < 4; ++dk) {
            float4 wv4 = *(const float4*)&W[(size_t)(k4 * 4 + dk) * DIM + tc * 4];
            w[dk][0] = wv4.x; w[dk][1] = wv4.y; w[dk][2] = wv4.z; w[dk][3] = wv4.w;
        }
#pragma unroll
        for (int i = 0; i < 8; ++i) {
            float4 a = *(const float4*)&As[(tr * 8 + i) * DIM + k4 * 4];
            float av[4] = {a.x, a.y, a.z, a.w};
#pragma unroll
            for (int dk = 0; dk < 4; ++dk)
#pragma unroll
                for (int j = 0; j < 4; ++j)
                    acc[i][j] += av[dk] * w[dk][j];
        }
    }

#pragma unroll
    for (int i = 0; i < 8; ++i) {
        int row = row0 + tr * 8 + i;
        if (row >= n) continue;
        float s = nrm[row];
        float4 v = make_float4(acc[i][0], acc[i][1], acc[i][2], acc[i][3]);
        v.x = fmaxf(v.x, 0.f) * s; v.y = fmaxf(v.y, 0.f) * s;
        v.z = fmaxf(v.z, 0.f) * s; v.w = fmaxf(v.w, 0.f) * s;
        __half2 lo = __float22half2_rn(make_float2(v.x, v.y));
        __half2 hi = __float22half2_rn(make_float2(v.z, v.w));
        uint2 u;
        u.x = *(unsigned int*)&lo;
        u.y = *(unsigned int*)&hi;
        *(uint2*)&outh[(size_t)row * DIM + tc * 4] = u;
    }
}

// Layer-3 GEMM: fp16 A[64x128] @ fp32 W3[128x40] -> fp16 out [n][40].
__global__ __launch_bounds__(256) void gemm3_kernel(
        const __half* __restrict__ Ah, const float* __restrict__ W,
        __half* __restrict__ outh, int n, int outw) {
    __shared__ float As[64 * DIM];
    int t = threadIdx.x;
    int row0 = blockIdx.x * 64;
    for (int q = t; q < 64 * 32; q += 256) {
        int r = q >> 5, c4 = q & 31;
        int row = row0 + r;
        float4 v = make_float4(0.f, 0.f, 0.f, 0.f);
        if (row < n) {
            uint2 u = *(const uint2*)&Ah[(size_t)row * DIM + c4 * 4];
            float2 f0 = __half22float2(*(__half2*)&u.x);
            float2 f1 = __half22float2(*(__half2*)&u.y);
            v = make_float4(f0.x, f0.y, f1.x, f1.y);
        }
        *(float4*)&As[r * DIM + c4 * 4] = v;
    }
    __syncthreads();

    int tc = t & 31, tr = t >> 5;
    if (tc >= 10) return;                  // 40 cols = 10 x (4 halves)
    float acc[8][4];
#pragma unroll
    for (int i = 0; i < 8; ++i)
#pragma unroll
        for (int j = 0; j < 4; ++j) acc[i][j] = 0.f;

    for (int k4 = 0; k4 < 32; ++k4) {
        float w[4][4];
#pragma unroll
        for (int dk = 0; dk < 4; ++dk) {
            float4 wv4 = *(const float4*)&W[(size_t)(k4 * 4 + dk) * outw + tc * 4];
            w[dk][0] = wv4.x; w[dk][1] = wv4.y; w[dk][2] = wv4.z; w[dk][3] = wv4.w;
        }
#pragma unroll
        for (int i = 0; i < 8; ++i) {
            float4 a = *(const float4*)&As[(tr * 8 + i) * DIM + k4 * 4];
            float av[4] = {a.x, a.y, a.z, a.w};
#pragma unroll
            for (int dk = 0; dk < 4; ++dk)
#pragma unroll
                for (int j = 0; j < 4; ++j)
                    acc[i][j] += av[dk] * w[dk][j];
        }
    }

#pragma unroll
    for (int i = 0; i < 8; ++i) {
        int row = row0 + tr * 8 + i;
        if (row >= n) continue;
        __half2 lo = __float22half2_rn(make_float2(acc[i][0], acc[i][1]));
        __half2 hi = __float22half2_rn(make_float2(acc[i][2], acc[i][3]));
        uint2 u;
        u.x = *(unsigned int*)&lo;
        u.y = *(unsigned int*)&hi;
        *(uint2*)&outh[(size_t)row * outw + tc * 4] = u;
    }
}

// Final agg over fp16 [N][40] rows -> fp32 d_out [N][40]. 16-lane group per
// node, pos<10 active (uint2 = 4 halves each), 4-deep edge ILP.
__global__ __launch_bounds__(256) void agg40_kernel(
        const __half* __restrict__ hin, const float* __restrict__ nrm,
        const int* __restrict__ off, const int* __restrict__ csr,
        float* __restrict__ out, int N) {
    int t = threadIdx.x;
    int lane = t & 63, wv = t >> 6;
    int g = lane >> 4, pos = lane & 15;
    int node = blockIdx.x * 16 + wv * 4 + g;
    if (node >= N || pos >= 10) return;
    int b = off[node], e = off[node + 1];
    float4 a0 = make_float4(0,0,0,0), a1 = a0, a2 = a0, a3 = a0;
    int j = b;
    for (; j + 3 < e; j += 4) {
        int s0 = csr[j], s1 = csr[j+1], s2 = csr[j+2], s3 = csr[j+3];
        uint2 u0 = *(const uint2*)&hin[(size_t)s0 * 40 + pos * 4];
        uint2 u1 = *(const uint2*)&hin[(size_t)s1 * 40 + pos * 4];
        uint2 u2 = *(const uint2*)&hin[(size_t)s2 * 40 + pos * 4];
        uint2 u3 = *(const uint2*)&hin[(size_t)s3 * 40 + pos * 4];
        float2 f;
        f = __half22float2(*(__half2*)&u0.x); a0.x+=f.x; a0.y+=f.y;
        f = __half22float2(*(__half2*)&u0.y); a0.z+=f.x; a0.w+=f.y;
        f = __half22float2(*(__half2*)&u1.x); a1.x+=f.x; a1.y+=f.y;
        f = __half22float2(*(__half2*)&u1.y); a1.z+=f.x; a1.w+=f.y;
        f = __half22float2(*(__half2*)&u2.x); a2.x+=f.x; a2.y+=f.y;
        f = __half22float2(*(__half2*)&u2.y); a2.z+=f.x; a2.w+=f.y;
        f = __half22float2(*(__half2*)&u3.x); a3.x+=f.x; a3.y+=f.y;
        f = __half22float2(*(__half2*)&u3.y); a3.z+=f.x; a3.w+=f.y;
    }
    for (; j < e; ++j) {
        uint2 u = *(const uint2*)&hin[(size_t)csr[j] * 40 + pos * 4];
        float2 f;
        f = __half22float2(*(__half2*)&u.x); a0.x+=f.x; a0.y+=f.y;
        f = __half22float2(*(__half2*)&u.y); a0.z+=f.x; a0.w+=f.y;
    }
    float s = nrm[node];
    float4 r;
    r.x = ((a0.x+a1.x) + (a2.x+a3.x)) * s;
    r.y = ((a0.y+a1.y) + (a2.y+a3.y)) * s;
    r.z = ((a0.z+a1.z) + (a2.z+a3.z)) * s;
    r.w = ((a0.w+a1.w) + (a2.w+a3.w)) * s;
    *(float4*)&out[(size_t)node * 40 + pos * 4] = r;
}

extern "C" void kernel_launch(void* const* d_in, const int* in_sizes, int n_in,
                              void* d_out, int out_size, void* d_ws, size_t ws_size,
                              hipStream_t stream) {
    const float* features = (const float*)d_in[0];
    const int*   edges    = (const int*)d_in[1];
    const float* W0       = (const float*)d_in[2];
    const float* W1       = (const float*)d_in[3];
    const float* W2       = (const float*)d_in[4];
    const float* W3       = (const float*)d_in[5];

    const int N = in_sizes[0] / DIM;       // 50000
    const int E = in_sizes[1] / 2;         // 640000
    const int DOUT = out_size / N;         // 40
    const int* src = edges;
    const int* dst = edges + E;

    char* p = (char*)d_ws;
    __half* featH = (__half*)p; p += (size_t)N * DIM * 2;   // prescaled features
    __half* agg16 = (__half*)p; p += (size_t)N * DIM * 2;   // agg out (pre-GEMM)
    __half* h16   = (__half*)p; p += (size_t)N * DIM * 2;   // gemm out (h1/h2/h3)
    __half* g3h   = (__half*)p; p += (size_t)N * 64 * 2;    // gemm3 out [N][40]
    float*  nrm   = (float*)p;  p += (size_t)N * 4;
    int*    deg   = (int*)p;    p += (size_t)N * 4;
    int*    cur   = (int*)p;    p += (size_t)N * 4;
    int*    off   = (int*)p;    p += (size_t)(N + 1) * 4;
    int*    bsum  = (int*)p;    p += 64 * 4;
    int*    csr   = (int*)p;    p += (size_t)E * 4;
    (void)ws_size; (void)n_in;

    hipMemsetAsync(deg, 0, (size_t)N * sizeof(int), stream);

    int eb = (E + 255) / 256;
    int G  = (N + CHUNK - 1) / CHUNK;      // 49
    deg_kernel   <<<eb, 256, 0, stream>>>(dst, deg, E);
    scanA_kernel <<<G, 256, 0, stream>>>(deg, nrm, bsum, N);
    scanBC_kernel<<<G, 256, 0, stream>>>(deg, bsum, off, cur, N, G);
    fill_kernel  <<<eb, 256, 0, stream>>>(src, dst, off, cur, csr, E);

    int n4 = N * (DIM / 4);
    conv_kernel<<<(n4 + 255) / 256, 256, 0, stream>>>(features, nrm, featH, n4);

    int gb = (N + 63) / 64;
    int ab = (N + 3) / 4;
    aggh_kernel<<<ab, 256, 0, stream>>>(featH, nrm, off, csr, agg16, N);
    gemm_kernel<<<gb, 256, 0, stream>>>(agg16, W0, nrm, h16, N);

    aggh_kernel<<<ab, 256, 0, stream>>>(h16, nrm, off, csr, agg16, N);
    gemm_kernel<<<gb, 256, 0, stream>>>(agg16, W1, nrm, h16, N);

    aggh_kernel<<<ab, 256, 0, stream>>>(h16, nrm, off, csr, agg16, N);
    gemm_kernel<<<gb, 256, 0, stream>>>(agg16, W2, nrm, h16, N);

    // layer 3: fp16 GEMM (128->40) -> fp16 rows, then gather 80B rows
    gemm3_kernel<<<gb, 256, 0, stream>>>(h16, W3, g3h, N, DOUT);
    agg40_kernel<<<(N + 15) / 16, 256, 0, stream>>>(g3h, nrm, off, csr,
                                                    (float*)d_out, N);
}

// Round 12
// 261.442 us; speedup vs baseline: 1.6948x; 1.1411x over previous
//
#include <hip/hip_runtime.h>
#include <hip/hip_fp16.h>

// GCN: 4 layers, N=50000, E=640000, d=128 (last 128->40).
// R12: GEMMs moved to MFMA (v_mfma_f32_16x16x32_f16) — inputs already fp16
// since R11. W converted once to fp16 TRANSPOSED Wt[c][k] (contiguous
// B-fragments). A-fragments read directly from global (row-major fp16, 16B
// per lane). fp32 accumulate; epilogue relu+nrm fp16 pack unchanged.
// Everything else identical to R11 (agg at the gather wall is the control).

#define DIM 128
#define CHUNK 1024        // scan chunk

typedef __attribute__((ext_vector_type(8))) _Float16 f16x8;
typedef __attribute__((ext_vector_type(4))) float f32x4;

__global__ void deg_kernel(const int* __restrict__ dst, int* __restrict__ deg, int E) {
    int i = blockIdx.x * blockDim.x + threadIdx.x;
    if (i < E) atomicAdd(&deg[dst[i]], 1);
}

// Phase A: per-chunk sums of deg; also computes nrm = rsqrt(max(deg,1)).
__global__ __launch_bounds__(256) void scanA_kernel(
        const int* __restrict__ deg, float* __restrict__ nrm,
        int* __restrict__ bsum, int n) {
    int b = blockIdx.x, t = threadIdx.x;
    int base = b * CHUNK + t * 4;
    int s = 0;
    if (base + 3 < n) {
        int4 d = *(const int4*)&deg[base];
        s = d.x + d.y + d.z + d.w;
        float4 r;
        r.x = rsqrtf(fmaxf((float)d.x, 1.0f));
        r.y = rsqrtf(fmaxf((float)d.y, 1.0f));
        r.z = rsqrtf(fmaxf((float)d.z, 1.0f));
        r.w = rsqrtf(fmaxf((float)d.w, 1.0f));
        *(float4*)&nrm[base] = r;
    } else {
        for (int j = 0; j < 4; ++j) {
            int idx = base + j;
            if (idx < n) {
                int d = deg[idx];
                s += d;
                nrm[idx] = rsqrtf(fmaxf((float)d, 1.0f));
            }
        }
    }
    for (int o = 32; o; o >>= 1) s += __shfl_down(s, o, 64);
    __shared__ int ws[4];
    if ((t & 63) == 0) ws[t >> 6] = s;
    __syncthreads();
    if (t == 0) bsum[b] = ws[0] + ws[1] + ws[2] + ws[3];
}

// Merged B+C: wave 0 scans bsum[G] in registers; zero cur; per-chunk offsets.
__global__ __launch_bounds__(256) void scanBC_kernel(
        const int* __restrict__ deg, const int* __restrict__ bsum,
        int* __restrict__ off, int* __restrict__ cur, int n, int G) {
    __shared__ int pbs;
    __shared__ int wsum[4];
    int b = blockIdx.x, t = threadIdx.x;
    if (t < 64) {
        int orig = (t < G) ? bsum[t] : 0;
        int v = orig;
        for (int o = 1; o < 64; o <<= 1) {
            int u = __shfl_up(v, o, 64);
            if (t >= o) v += u;
        }
        if (b == 0 && t == G - 1) off[n] = v;   // grand total
        if (t == b) pbs = v - orig;             // exclusive prefix of chunk b
    }
    int base = b * CHUNK + t * 4;
    if (base + 3 < n) *(int4*)&cur[base] = make_int4(0, 0, 0, 0);
    else for (int j = 0; j < 4; ++j) if (base + j < n) cur[base + j] = 0;

    int d0 = 0, d1 = 0, d2 = 0, d3 = 0;
    if (base + 3 < n) {
        int4 d = *(const int4*)&deg[base];
        d0 = d.x; d1 = d.y; d2 = d.z; d3 = d.w;
    } else {
        if (base     < n) d0 = deg[base];
        if (base + 1 < n) d1 = deg[base + 1];
        if (base + 2 < n) d2 = deg[base + 2];
    }
    int tot = d0 + d1 + d2 + d3;
    int v = tot;
    for (int o = 1; o < 64; o <<= 1) {
        int u = __shfl_up(v, o, 64);
        if ((t & 63) >= o) v += u;
    }
    if ((t & 63) == 63) wsum[t >> 6] = v;
    __syncthreads();
    int wbase = 0;
    for (int w = 0; w < (t >> 6); ++w) wbase += wsum[w];
    int p = pbs + wbase + (v - tot);
    if (base + 3 < n) {
        int4 o4 = make_int4(p, p + d0, p + d0 + d1, p + d0 + d1 + d2);
        *(int4*)&off[base] = o4;
    } else {
        if (base     < n) off[base]     = p;
        if (base + 1 < n) off[base + 1] = p + d0;
        if (base + 2 < n) off[base + 2] = p + d0 + d1;
    }
}

__global__ void fill_kernel(const int* __restrict__ src, const int* __restrict__ dst,
                            const int* __restrict__ off, int* __restrict__ cur,
                            int* __restrict__ csr, int E) {
    int i = blockIdx.x * blockDim.x + threadIdx.x;
    if (i < E) {
        int d = dst[i];
        int p = atomicAdd(&cur[d], 1);
        csr[off[d] + p] = src[i];
    }
}

// featH[r] = features[r] * nrm[r], fp16.
__global__ void conv_kernel(const float* __restrict__ f, const float* __restrict__ nrm,
                            __half* __restrict__ out, int n4) {
    int i = blockIdx.x * blockDim.x + threadIdx.x;
    if (i < n4) {
        int r = i >> 5, c4 = i & 31;
        float s = nrm[r];
        float4 v = ((const float4*)f)[i];
        __half2 lo = __float22half2_rn(make_float2(v.x * s, v.y * s));
        __half2 hi = __float22half2_rn(make_float2(v.z * s, v.w * s));
        uint2 u;
        u.x = *(unsigned int*)&lo;
        u.y = *(unsigned int*)&hi;
        *(uint2*)&out[(size_t)r * DIM + c4 * 4] = u;
    }
}

// Wt: fp16 transposed weights. Layers 0..2: Wt_l[c*128+k] = W_l[k*128+c]
// (l*16384 offset). Layer 3 (offset 3*16384): Wt3[c*128+k] = c<40 ?
// W3[k*40+c] : 0, c in [0,48).
__global__ void convW_kernel(const float* __restrict__ W0, const float* __restrict__ W1,
                             const float* __restrict__ W2, const float* __restrict__ W3,
                             __half* __restrict__ Wt) {
    int i = blockIdx.x * blockDim.x + threadIdx.x;
    if (i < 3 * 128 * 128) {
        int l = i >> 14;
        int c = (i >> 7) & 127, k = i & 127;
        const float* W = (l == 0) ? W0 : ((l == 1) ? W1 : W2);
        Wt[i] = __float2half(W[k * 128 + c]);
    } else if (i < 3 * 128 * 128 + 48 * 128) {
        int j = i - 3 * 128 * 128;
        int c = j >> 7, k = j & 127;
        Wt[i] = __float2half((c < 40) ? W3[k * 40 + c] : 0.f);
    }
}

// fp16 gather (unchanged from R11): quarter-wave per edge, uint4 row chunks.
__global__ __launch_bounds__(256) void aggh_kernel(
        const __half* __restrict__ hin, const float* __restrict__ nrm,
        const int* __restrict__ off, const int* __restrict__ csr,
        __half* __restrict__ out, int N) {
    int t = threadIdx.x;
    int lane = t & 63;
    int node = blockIdx.x * 4 + (t >> 6);
    if (node >= N) return;
    int pos = lane & 15, sg = lane >> 4;
    int c = pos * 8;
    int b = off[node], e = off[node + 1];
    float a[8] = {0,0,0,0,0,0,0,0};
    float bb[8] = {0,0,0,0,0,0,0,0};
    int j = b + sg;
    for (; j + 4 < e; j += 8) {
        int s0 = csr[j], s1 = csr[j + 4];
        uint4 u0 = *(const uint4*)&hin[(size_t)s0 * DIM + c];
        uint4 u1 = *(const uint4*)&hin[(size_t)s1 * DIM + c];
        float2 f;
        f = __half22float2(*(__half2*)&u0.x); a[0]+=f.x; a[1]+=f.y;
        f = __half22float2(*(__half2*)&u0.y); a[2]+=f.x; a[3]+=f.y;
        f = __half22float2(*(__half2*)&u0.z); a[4]+=f.x; a[5]+=f.y;
        f = __half22float2(*(__half2*)&u0.w); a[6]+=f.x; a[7]+=f.y;
        f = __half22float2(*(__half2*)&u1.x); bb[0]+=f.x; bb[1]+=f.y;
        f = __half22float2(*(__half2*)&u1.y); bb[2]+=f.x; bb[3]+=f.y;
        f = __half22float2(*(__half2*)&u1.z); bb[4]+=f.x; bb[5]+=f.y;
        f = __half22float2(*(__half2*)&u1.w); bb[6]+=f.x; bb[7]+=f.y;
    }
    for (; j < e; j += 4) {
        uint4 u = *(const uint4*)&hin[(size_t)csr[j] * DIM + c];
        float2 f;
        f = __half22float2(*(__half2*)&u.x); a[0]+=f.x; a[1]+=f.y;
        f = __half22float2(*(__half2*)&u.y); a[2]+=f.x; a[3]+=f.y;
        f = __half22float2(*(__half2*)&u.z); a[4]+=f.x; a[5]+=f.y;
        f = __half22float2(*(__half2*)&u.w); a[6]+=f.x; a[7]+=f.y;
    }
#pragma unroll
    for (int k = 0; k < 8; ++k) a[k] += bb[k];
#pragma unroll
    for (int k = 0; k < 8; ++k) {
        a[k] += __shfl_xor(a[k], 16, 64);
        a[k] += __shfl_xor(a[k], 32, 64);
    }
    if (sg == 0) {
        float s = nrm[node];
        __half2 h0 = __float22half2_rn(make_float2(a[0]*s, a[1]*s));
        __half2 h1 = __float22half2_rn(make_float2(a[2]*s, a[3]*s));
        __half2 h2 = __float22half2_rn(make_float2(a[4]*s, a[5]*s));
        __half2 h3 = __float22half2_rn(make_float2(a[6]*s, a[7]*s));
        uint4 u;
        u.x = *(unsigned int*)&h0; u.y = *(unsigned int*)&h1;
        u.z = *(unsigned int*)&h2; u.w = *(unsigned int*)&h3;
        *(uint4*)&out[(size_t)node * DIM + c] = u;
    }
}

// MFMA GEMM: C[64x128] = A(fp16)[64x128] @ W(fp16 Wt[c][k])[128x128].
// 4 waves, each 16 rows x 128 cols. A-frag: lane holds A[row0+(l&15)]
// [(l>>4)*8 + j + 32*k0] (16B contiguous). B-frag: Wt[(ct*16+(l&15))*128 +
// (l>>4)*8 + 32*k0]. C/D: col=l&15, row=(l>>4)*4+reg [m89-verified].
// Epilogue: relu + nrm[row], fp16 pack (2B stores, 32B coalesced segments).
__global__ __launch_bounds__(256) void gemmM_kernel(
        const __half* __restrict__ Ah, const __half* __restrict__ Wt,
        const float* __restrict__ nrm, __half* __restrict__ outh, int n) {
    int t = threadIdx.x;
    int lane = t & 63, wv = t >> 6;
    int row0 = blockIdx.x * 64 + wv * 16;
    int arow = row0 + (lane & 15);
    int ar = (arow < n) ? arow : (n - 1);
    int kg = lane >> 4;

    const __half* Abase = Ah + (size_t)ar * DIM + kg * 8;
    f16x8 a[4];
#pragma unroll
    for (int k0 = 0; k0 < 4; ++k0)
        a[k0] = *(const f16x8*)(Abase + k0 * 32);

    f32x4 acc[8];
#pragma unroll
    for (int ct = 0; ct < 8; ++ct) {
        acc[ct] = (f32x4){0.f, 0.f, 0.f, 0.f};
        const __half* Bbase = Wt + (size_t)(ct * 16 + (lane & 15)) * DIM + kg * 8;
#pragma unroll
        for (int k0 = 0; k0 < 4; ++k0) {
            f16x8 b = *(const f16x8*)(Bbase + k0 * 32);
            acc[ct] = __builtin_amdgcn_mfma_f32_16x16x32_f16(a[k0], b, acc[ct], 0, 0, 0);
        }
    }

    int col = lane & 15;
    int rbase = row0 + (lane >> 4) * 4;
#pragma unroll
    for (int r = 0; r < 4; ++r) {
        int row = rbase + r;
        if (row >= n) continue;
        float s = nrm[row];
#pragma unroll
        for (int ct = 0; ct < 8; ++ct) {
            float v = fmaxf(acc[ct][r], 0.f) * s;
            outh[(size_t)row * DIM + ct * 16 + col] = __float2half(v);
        }
    }
}

// MFMA layer-3 GEMM: fp16 A[64x128] @ Wt3[48][128] -> fp16 out [n][40]
// (3 col-tiles, store guarded col<40). No relu/scale.
__global__ __launch_bounds__(256) void gemm3M_kernel(
        const __half* __restrict__ Ah, const __half* __restrict__ Wt3,
        __half* __restrict__ outh, int n) {
    int t = threadIdx.x;
    int lane = t & 63, wv = t >> 6;
    int row0 = blockIdx.x * 64 + wv * 16;
    int arow = row0 + (lane & 15);
    int ar = (arow < n) ? arow : (n - 1);
    int kg = lane >> 4;

    const __half* Abase = Ah + (size_t)ar * DIM + kg * 8;
    f16x8 a[4];
#pragma unroll
    for (int k0 = 0; k0 < 4; ++k0)
        a[k0] = *(const f16x8*)(Abase + k0 * 32);

    f32x4 acc[3];
#pragma unroll
    for (int ct = 0; ct < 3; ++ct) {
        acc[ct] = (f32x4){0.f, 0.f, 0.f, 0.f};
        const __half* Bbase = Wt3 + (size_t)(ct * 16 + (lane & 15)) * DIM + kg * 8;
#pragma unroll
        for (int k0 = 0; k0 < 4; ++k0) {
            f16x8 b = *(const f16x8*)(Bbase + k0 * 32);
            acc[ct] = __builtin_amdgcn_mfma_f32_16x16x32_f16(a[k0], b, acc[ct], 0, 0, 0);
        }
    }

    int col = lane & 15;
    int rbase = row0 + (lane >> 4) * 4;
#pragma unroll
    for (int r = 0; r < 4; ++r) {
        int row = rbase + r;
        if (row >= n) continue;
#pragma unroll
        for (int ct = 0; ct < 3; ++ct) {
            int cc = ct * 16 + col;
            if (cc < 40)
                outh[(size_t)row * 40 + cc] = __float2half(acc[ct][r]);
        }
    }
}

// Final agg over fp16 [N][40] rows -> fp32 d_out. 16-lane group per node.
__global__ __launch_bounds__(256) void agg40_kernel(
        const __half* __restrict__ hin, const float* __restrict__ nrm,
        const int* __restrict__ off, const int* __restrict__ csr,
        float* __restrict__ out, int N) {
    int t = threadIdx.x;
    int lane = t & 63, wv = t >> 6;
    int g = lane >> 4, pos = lane & 15;
    int node = blockIdx.x * 16 + wv * 4 + g;
    if (node >= N || pos >= 10) return;
    int b = off[node], e = off[node + 1];
    float4 a0 = make_float4(0,0,0,0), a1 = a0, a2 = a0, a3 = a0;
    int j = b;
    for (; j + 3 < e; j += 4) {
        int s0 = csr[j], s1 = csr[j+1], s2 = csr[j+2], s3 = csr[j+3];
        uint2 u0 = *(const uint2*)&hin[(size_t)s0 * 40 + pos * 4];
        uint2 u1 = *(const uint2*)&hin[(size_t)s1 * 40 + pos * 4];
        uint2 u2 = *(const uint2*)&hin[(size_t)s2 * 40 + pos * 4];
        uint2 u3 = *(const uint2*)&hin[(size_t)s3 * 40 + pos * 4];
        float2 f;
        f = __half22float2(*(__half2*)&u0.x); a0.x+=f.x; a0.y+=f.y;
        f = __half22float2(*(__half2*)&u0.y); a0.z+=f.x; a0.w+=f.y;
        f = __half22float2(*(__half2*)&u1.x); a1.x+=f.x; a1.y+=f.y;
        f = __half22float2(*(__half2*)&u1.y); a1.z+=f.x; a1.w+=f.y;
        f = __half22float2(*(__half2*)&u2.x); a2.x+=f.x; a2.y+=f.y;
        f = __half22float2(*(__half2*)&u2.y); a2.z+=f.x; a2.w+=f.y;
        f = __half22float2(*(__half2*)&u3.x); a3.x+=f.x; a3.y+=f.y;
        f = __half22float2(*(__half2*)&u3.y); a3.z+=f.x; a3.w+=f.y;
    }
    for (; j < e; ++j) {
        uint2 u = *(const uint2*)&hin[(size_t)csr[j] * 40 + pos * 4];
        float2 f;
        f = __half22float2(*(__half2*)&u.x); a0.x+=f.x; a0.y+=f.y;
        f = __half22float2(*(__half2*)&u.y); a0.z+=f.x; a0.w+=f.y;
    }
    float s = nrm[node];
    float4 r;
    r.x = ((a0.x+a1.x) + (a2.x+a3.x)) * s;
    r.y = ((a0.y+a1.y) + (a2.y+a3.y)) * s;
    r.z = ((a0.z+a1.z) + (a2.z+a3.z)) * s;
    r.w = ((a0.w+a1.w) + (a2.w+a3.w)) * s;
    *(float4*)&out[(size_t)node * 40 + pos * 4] = r;
}

extern "C" void kernel_launch(void* const* d_in, const int* in_sizes, int n_in,
                              void* d_out, int out_size, void* d_ws, size_t ws_size,
                              hipStream_t stream) {
    const float* features = (const float*)d_in[0];
    const int*   edges    = (const int*)d_in[1];
    const float* W0       = (const float*)d_in[2];
    const float* W1       = (const float*)d_in[3];
    const float* W2       = (const float*)d_in[4];
    const float* W3       = (const float*)d_in[5];

    const int N = in_sizes[0] / DIM;       // 50000
    const int E = in_sizes[1] / 2;         // 640000
    const int* src = edges;
    const int* dst = edges + E;

    char* p = (char*)d_ws;
    __half* featH = (__half*)p; p += (size_t)N * DIM * 2;   // prescaled features
    __half* agg16 = (__half*)p; p += (size_t)N * DIM * 2;   // agg out (pre-GEMM)
    __half* h16   = (__half*)p; p += (size_t)N * DIM * 2;   // gemm out (h1/h2/h3)
    __half* g3h   = (__half*)p; p += (size_t)N * 64 * 2;    // gemm3 out [N][40]
    __half* Wt    = (__half*)p; p += (size_t)(3 * 128 * 128 + 48 * 128) * 2;
    float*  nrm   = (float*)p;  p += (size_t)N * 4;
    int*    deg   = (int*)p;    p += (size_t)N * 4;
    int*    cur   = (int*)p;    p += (size_t)N * 4;
    int*    off   = (int*)p;    p += (size_t)(N + 1) * 4;
    int*    bsum  = (int*)p;    p += 64 * 4;
    int*    csr   = (int*)p;    p += (size_t)E * 4;
    (void)ws_size; (void)n_in;

    hipMemsetAsync(deg, 0, (size_t)N * sizeof(int), stream);

    int eb = (E + 255) / 256;
    int G  = (N + CHUNK - 1) / CHUNK;      // 49
    deg_kernel   <<<eb, 256, 0, stream>>>(dst, deg, E);
    scanA_kernel <<<G, 256, 0, stream>>>(deg, nrm, bsum, N);
    scanBC_kernel<<<G, 256, 0, stream>>>(deg, bsum, off, cur, N, G);
    fill_kernel  <<<eb, 256, 0, stream>>>(src, dst, off, cur, csr, E);

    int wB = (3 * 128 * 128 + 48 * 128 + 255) / 256;
    convW_kernel<<<wB, 256, 0, stream>>>(W0, W1, W2, W3, Wt);

    int n4 = N * (DIM / 4);
    conv_kernel<<<(n4 + 255) / 256, 256, 0, stream>>>(features, nrm, featH, n4);

    int gb = (N + 63) / 64;
    int ab = (N + 3) / 4;
    aggh_kernel<<<ab, 256, 0, stream>>>(featH, nrm, off, csr, agg16, N);
    gemmM_kernel<<<gb, 256, 0, stream>>>(agg16, Wt, nrm, h16, N);

    aggh_kernel<<<ab, 256, 0, stream>>>(h16, nrm, off, csr, agg16, N);
    gemmM_kernel<<<gb, 256, 0, stream>>>(agg16, Wt + 128 * 128, nrm, h16, N);

    aggh_kernel<<<ab, 256, 0, stream>>>(h16, nrm, off, csr, agg16, N);
    gemmM_kernel<<<gb, 256, 0, stream>>>(agg16, Wt + 2 * 128 * 128, nrm, h16, N);

    // layer 3: MFMA GEMM (128->40) -> fp16 rows, then gather 80B rows
    gemm3M_kernel<<<gb, 256, 0, stream>>>(h16, Wt + 3 * 128 * 128, g3h, N);
    agg40_kernel<<<(N + 15) / 16, 256, 0, stream>>>(g3h, nrm, off, csr,
                                                    (float*)d_out, N);
}